// Round 1
// baseline (4625.175 us; speedup 1.0000x reference)
//
#include <hip/hip_runtime.h>
#include <cmath>

// Problem constants (from reference)
#define IN_DIM   256
#define PE_DIM   512
#define FEAT_DIM 768      // IN_DIM + PE_DIM
#define H0_DIM   512
#define H1_DIM   256
#define BOT      128
#define OUT_DIM  4
#define NQ_      131072
#define NE_      262144
#define CH       32768    // edge chunk
#define NCHUNK   (NE_/CH)

// Workspace layout (bytes). Total required: 320 MB.
//   [0,        96MB)  feat_c  (CH*768*4)        -- live during chunk loop
//   [96MB,    160MB)  h0_c    (CH*512*4)
//   [160MB,   192MB)  h1_c    (CH*256*4)
//   [192MB,   320MB)  h2_full (E*128*4)         -- live until seg_mean
//   [0,       128MB)  g1      (NQ*256*4)        -- reuses feat/h0 (dead after loop)
//   [128MB,   192MB)  mean    (NQ*128*4)        -- reuses h0-tail/h1 (dead after loop)
static const size_t OFF_H0   = 100663296;   // 96MB
static const size_t OFF_H1   = 167772160;   // 160MB
static const size_t OFF_H2   = 201326592;   // 192MB
static const size_t OFF_G1   = 0;
static const size_t OFF_MEAN = 134217728;   // 128MB

__device__ __forceinline__ float gelu_f(float v) {
    return v * 0.5f * (1.0f + erff(v * 0.7071067811865476f));
}

// ---------------------------------------------------------------------------
// feat[le][0:256]   = x[gidx[e]]
// feat[le][256+c*128+j] = sin/cos(coords[c] * omega[j%64]),  coords = qp/100-1 ++ [1]
// one block (256 thr) per edge
// ---------------------------------------------------------------------------
__global__ __launch_bounds__(256) void build_feat(
    const float* __restrict__ x, const float* __restrict__ qpos,
    const int* __restrict__ edges, float* __restrict__ feat, int ebase)
{
    const int le = blockIdx.x;
    const int e  = ebase + le;
    const int t  = threadIdx.x;
    const int q  = edges[2*e];
    const int g  = edges[2*e + 1];

    // x part (coalesced 256-float row gather)
    feat[(size_t)le * FEAT_DIM + t] = x[(size_t)g * IN_DIM + t];

    // pe part: cols 256..767
    #pragma unroll
    for (int p = 0; p < 2; ++p) {
        int idx = t + 256 * p;          // 0..511
        int c   = idx >> 7;             // coord index 0..3
        int j   = idx & 127;            // 0..127
        float cv = (c < 3) ? (qpos[q * 3 + c] * 0.01f - 1.0f) : 1.0f;
        int jj = j & 63;
        // omega[jj] = 10000^(-jj/64) = exp(-jj * ln(10000)/64)
        float om  = expf(-(float)jj * (9.210340371976184f / 64.0f));
        float arg = cv * om;
        float v   = (j < 64) ? sinf(arg) : cosf(arg);
        feat[(size_t)le * FEAT_DIM + IN_DIM + idx] = v;
    }
}

// ---------------------------------------------------------------------------
// C[M,N] = act(A[M,K] @ W[K,N] + bias[N]) , all fp32 row-major.
// BM=BN=128, BK=16, 256 threads, 8x8 microtile (two 4-wide groups 64 apart
// in each dim so LDS float4 reads are <=2-way bank aliased == free).
// Requires M%128==0, N%128==0, K%16==0 (all satisfied here).
// ---------------------------------------------------------------------------
template <int ACT>
__global__ __launch_bounds__(256) void gemm_bias_act(
    const float* __restrict__ A, const float* __restrict__ W,
    const float* __restrict__ bias, float* __restrict__ C,
    int M, int K, int N)
{
    __shared__ float As[16][132];   // [k][m], +4 pad kills write conflicts
    __shared__ float Ws[16][128];   // [k][n]

    const int tid = threadIdx.x;
    const int tx  = tid & 15;       // col group 0..15
    const int ty  = tid >> 4;       // row group 0..15
    const int bn  = blockIdx.x * 128;
    const int bm  = blockIdx.y * 128;

    const int ar = tid >> 4;        // 0..15  (A tile row base)
    const int ac = tid & 15;        // 0..15  (A tile k)
    const int wn = tid & 127;       // 0..127 (W tile col)
    const int wk = tid >> 7;        // 0..1   (W tile k base)

    float acc[8][8];
    #pragma unroll
    for (int i = 0; i < 8; ++i)
        #pragma unroll
        for (int j = 0; j < 8; ++j) acc[i][j] = 0.0f;

    for (int k0 = 0; k0 < K; k0 += 16) {
        #pragma unroll
        for (int i = 0; i < 8; ++i) {
            int r = ar + 16 * i;
            As[ac][r] = A[(size_t)(bm + r) * K + (k0 + ac)];
        }
        #pragma unroll
        for (int i = 0; i < 8; ++i) {
            int kk = wk + 2 * i;
            Ws[kk][wn] = W[(size_t)(k0 + kk) * N + (bn + wn)];
        }
        __syncthreads();
        #pragma unroll
        for (int k = 0; k < 16; ++k) {
            float4 a0 = *(const float4*)&As[k][ty * 4];
            float4 a1 = *(const float4*)&As[k][64 + ty * 4];
            float4 b0 = *(const float4*)&Ws[k][tx * 4];
            float4 b1 = *(const float4*)&Ws[k][64 + tx * 4];
            float av[8] = {a0.x, a0.y, a0.z, a0.w, a1.x, a1.y, a1.z, a1.w};
            float bv[8] = {b0.x, b0.y, b0.z, b0.w, b1.x, b1.y, b1.z, b1.w};
            #pragma unroll
            for (int i = 0; i < 8; ++i)
                #pragma unroll
                for (int j = 0; j < 8; ++j)
                    acc[i][j] = fmaf(av[i], bv[j], acc[i][j]);
        }
        __syncthreads();
    }

    // epilogue: bias + activation + float4 stores
    float bv0[4], bv1[4];
    #pragma unroll
    for (int j = 0; j < 4; ++j) {
        bv0[j] = bias[bn + tx * 4 + j];
        bv1[j] = bias[bn + 64 + tx * 4 + j];
    }
    #pragma unroll
    for (int i = 0; i < 8; ++i) {
        int row = bm + ty * 4 + (i & 3) + ((i & 4) << 4);
        float* crow = C + (size_t)row * N + bn;
        float4 o0, o1;
        o0.x = acc[i][0] + bv0[0]; o0.y = acc[i][1] + bv0[1];
        o0.z = acc[i][2] + bv0[2]; o0.w = acc[i][3] + bv0[3];
        o1.x = acc[i][4] + bv1[0]; o1.y = acc[i][5] + bv1[1];
        o1.z = acc[i][6] + bv1[2]; o1.w = acc[i][7] + bv1[3];
        if (ACT) {
            o0.x = gelu_f(o0.x); o0.y = gelu_f(o0.y);
            o0.z = gelu_f(o0.z); o0.w = gelu_f(o0.w);
            o1.x = gelu_f(o1.x); o1.y = gelu_f(o1.y);
            o1.z = gelu_f(o1.z); o1.w = gelu_f(o1.w);
        }
        *(float4*)&crow[tx * 4]      = o0;
        *(float4*)&crow[64 + tx * 4] = o1;
    }
}

// ---------------------------------------------------------------------------
// segment mean over sorted qidx: one block (128 thr) per query, binary search
// for the edge range, sum h2 rows, divide by max(count,1).
// ---------------------------------------------------------------------------
__global__ __launch_bounds__(128) void seg_mean(
    const int* __restrict__ edges, const float* __restrict__ h2,
    float* __restrict__ mean)
{
    const int q = blockIdx.x;
    const int t = threadIdx.x;

    int lo = 0, hi = NE_;
    while (lo < hi) { int mid = (lo + hi) >> 1; if (edges[2 * mid] < q) lo = mid + 1; else hi = mid; }
    const int s = lo;
    hi = NE_;
    while (lo < hi) { int mid = (lo + hi) >> 1; if (edges[2 * mid] < q + 1) lo = mid + 1; else hi = mid; }
    const int e_end = lo;

    float acc = 0.0f;
    for (int e = s; e < e_end; ++e) acc += h2[(size_t)e * BOT + t];
    int cnt = e_end - s;
    mean[(size_t)q * BOT + t] = acc / (float)(cnt > 0 ? cnt : 1);
}

// ---------------------------------------------------------------------------
// out[NQ,4] = g1[NQ,256] @ pw1[256,4] + pb1 : one wave per row, shuffle reduce
// ---------------------------------------------------------------------------
__global__ __launch_bounds__(256) void pred1_kernel(
    const float* __restrict__ g1, const float* __restrict__ w,
    const float* __restrict__ b, float* __restrict__ out)
{
    const int wave = threadIdx.x >> 6;
    const int lane = threadIdx.x & 63;
    const int row  = blockIdx.x * 4 + wave;

    const float* g = g1 + (size_t)row * 256;
    float a0 = 0, a1 = 0, a2 = 0, a3 = 0;
    #pragma unroll
    for (int i = 0; i < 4; ++i) {
        int k = lane + 64 * i;
        float gv = g[k];
        const float* wr = w + k * 4;
        a0 = fmaf(gv, wr[0], a0);
        a1 = fmaf(gv, wr[1], a1);
        a2 = fmaf(gv, wr[2], a2);
        a3 = fmaf(gv, wr[3], a3);
    }
    #pragma unroll
    for (int off = 32; off > 0; off >>= 1) {
        a0 += __shfl_down(a0, off, 64);
        a1 += __shfl_down(a1, off, 64);
        a2 += __shfl_down(a2, off, 64);
        a3 += __shfl_down(a3, off, 64);
    }
    if (lane == 0) {
        float4 o = {a0 + b[0], a1 + b[1], a2 + b[2], a3 + b[3]};
        *(float4*)&out[(size_t)row * 4] = o;
    }
}

// ---------------------------------------------------------------------------
extern "C" void kernel_launch(void* const* d_in, const int* in_sizes, int n_in,
                              void* d_out, int out_size, void* d_ws, size_t ws_size,
                              hipStream_t stream)
{
    const float* x    = (const float*)d_in[0];
    const float* qpos = (const float*)d_in[1];
    const int*   edges= (const int*)  d_in[2];
    const float* w0   = (const float*)d_in[3];
    const float* b0   = (const float*)d_in[4];
    const float* w1   = (const float*)d_in[5];
    const float* b1   = (const float*)d_in[6];
    const float* w2   = (const float*)d_in[7];
    const float* b2   = (const float*)d_in[8];
    const float* pw0  = (const float*)d_in[9];
    const float* pb0  = (const float*)d_in[10];
    const float* pw1  = (const float*)d_in[11];
    const float* pb1  = (const float*)d_in[12];
    float* out = (float*)d_out;

    char* ws = (char*)d_ws;
    float* feat = (float*)(ws);
    float* h0   = (float*)(ws + OFF_H0);
    float* h1   = (float*)(ws + OFF_H1);
    float* h2   = (float*)(ws + OFF_H2);
    float* g1   = (float*)(ws + OFF_G1);
    float* mean = (float*)(ws + OFF_MEAN);

    for (int c = 0; c < NCHUNK; ++c) {
        const int ebase = c * CH;
        build_feat<<<CH, 256, 0, stream>>>(x, qpos, edges, feat, ebase);
        gemm_bias_act<1><<<dim3(H0_DIM / 128, CH / 128), 256, 0, stream>>>(
            feat, w0, b0, h0, CH, FEAT_DIM, H0_DIM);
        gemm_bias_act<1><<<dim3(H1_DIM / 128, CH / 128), 256, 0, stream>>>(
            h0, w1, b1, h1, CH, H0_DIM, H1_DIM);
        gemm_bias_act<0><<<dim3(BOT / 128, CH / 128), 256, 0, stream>>>(
            h1, w2, b2, h2 + (size_t)ebase * BOT, CH, H1_DIM, BOT);
    }

    seg_mean<<<NQ_, 128, 0, stream>>>(edges, h2, mean);
    gemm_bias_act<1><<<dim3(H1_DIM / 128, NQ_ / 128), 256, 0, stream>>>(
        mean, pw0, pb0, g1, NQ_, BOT, H1_DIM);
    pred1_kernel<<<NQ_ / 4, 256, 0, stream>>>(g1, pw1, pb1, out);
}

// Round 2
// 2686.044 us; speedup vs baseline: 1.7219x; 1.7219x over previous
//
#include <hip/hip_runtime.h>
#include <cmath>

// Problem constants
#define IN_DIM   256
#define PE_DIM   512
#define FEAT_DIM 768
#define H0_DIM   512
#define H1_DIM   256
#define BOT      128
#define NQ_      131072
#define NE_      262144
#define CH       16384
#define NCHUNK   (NE_/CH)

// Workspace layout (bytes), total 320 MB:
//  chunk-loop region [0,96MB): featH/L, h0H/L, h1H/L (bf16)
//  weights [96MB,~98.3MB): transposed hi/lo bf16 weights
//  h2 fp32 [192MB,320MB)
//  after loop: meanH/L at [0,64MB); g1 fp32 reuses h2 region
static const size_t OFF_FEATH = 0;
static const size_t OFF_FEATL = 25165824;
static const size_t OFF_H0H   = 50331648;
static const size_t OFF_H0L   = 67108864;
static const size_t OFF_H1H   = 83886080;
static const size_t OFF_H1L   = 92274688;
static const size_t OFF_W0H   = 100663296;
static const size_t OFF_W0L   = 101449728;
static const size_t OFF_W1H   = 102236160;
static const size_t OFF_W1L   = 102498304;
static const size_t OFF_W2H   = 102760448;
static const size_t OFF_W2L   = 102825984;
static const size_t OFF_PW0H  = 102891520;
static const size_t OFF_PW0L  = 102957056;
static const size_t OFF_H2    = 201326592;
static const size_t OFF_MEANH = 0;
static const size_t OFF_MEANL = 33554432;
static const size_t OFF_G1    = 201326592;

typedef __attribute__((ext_vector_type(8))) short bf16x8;
typedef __attribute__((ext_vector_type(4))) float f32x4;

__device__ __forceinline__ float gelu_f(float v) {
    return v * 0.5f * (1.0f + erff(v * 0.7071067811865476f));
}
__device__ __forceinline__ unsigned short f2bf(float f) {
    unsigned int u = __float_as_uint(f);
    unsigned int r = (u + 0x7FFFu + ((u >> 16) & 1u)) >> 16;
    return (unsigned short)r;
}
__device__ __forceinline__ float bf2f(unsigned short h) {
    return __uint_as_float(((unsigned int)h) << 16);
}
__device__ __forceinline__ void split_store(float v, unsigned short* ph, unsigned short* pl) {
    unsigned short h = f2bf(v);
    *ph = h;
    *pl = f2bf(v - bf2f(h));
}
__device__ __forceinline__ void stage16(const void* g, void* l) {
    __builtin_amdgcn_global_load_lds(
        (const __attribute__((address_space(1))) unsigned int*)g,
        (__attribute__((address_space(3))) unsigned int*)l,
        16, 0, 0);
}

// ---------------------------------------------------------------------------
// Weight convert: W[K][N] fp32 -> WT hi/lo bf16 [N][K]
// ---------------------------------------------------------------------------
__global__ __launch_bounds__(256) void conv_w(
    const float* __restrict__ W, unsigned short* __restrict__ WTh,
    unsigned short* __restrict__ WTl, int K, int N)
{
    int idx = blockIdx.x * 256 + threadIdx.x;
    if (idx >= K * N) return;
    int k = idx / N, n = idx % N;
    float v = W[idx];
    unsigned short h = f2bf(v);
    WTh[(size_t)n * K + k] = h;
    WTl[(size_t)n * K + k] = f2bf(v - bf2f(h));
}

// ---------------------------------------------------------------------------
// feat build -> bf16 hi/lo [CH][768]; one block per edge
// ---------------------------------------------------------------------------
__global__ __launch_bounds__(256) void build_feat(
    const float* __restrict__ x, const float* __restrict__ qpos,
    const int* __restrict__ edges,
    unsigned short* __restrict__ fH, unsigned short* __restrict__ fL, int ebase)
{
    const int le = blockIdx.x;
    const int e  = ebase + le;
    const int t  = threadIdx.x;
    const int q  = edges[2*e];
    const int g  = edges[2*e + 1];
    const size_t base = (size_t)le * FEAT_DIM;

    split_store(x[(size_t)g * IN_DIM + t], &fH[base + t], &fL[base + t]);

    #pragma unroll
    for (int p = 0; p < 2; ++p) {
        int idx = t + 256 * p;          // 0..511
        int c   = idx >> 7;             // coord 0..3
        int j   = idx & 127;
        float cv = (c < 3) ? (qpos[q * 3 + c] * 0.01f - 1.0f) : 1.0f;
        int jj = j & 63;
        float om  = expf(-(float)jj * (9.210340371976184f / 64.0f));
        float arg = cv * om;
        float v   = (j < 64) ? sinf(arg) : cosf(arg);
        split_store(v, &fH[base + IN_DIM + idx], &fL[base + IN_DIM + idx]);
    }
}

// ---------------------------------------------------------------------------
// Split-bf16 MFMA GEMM: C[M,N] = act(A[M,K] @ W[K,N] + bias) where
// A given as hi/lo bf16 [M][K], W given transposed hi/lo bf16 [N][K].
// C ~= Ah*Bh + Ah*Bl + Al*Bh (3 MFMA passes). 128x128 tile, BK=32,
// 256 thr = 4 waves, each wave 64x64 quadrant = 4x4 16x16x32 tiles.
// OUT_MODE 0: fp32 out; 1: bf16 hi/lo out.
// ---------------------------------------------------------------------------
template <int ACT, int OUT_MODE>
__global__ __launch_bounds__(256) void gemm_mfma(
    const unsigned short* __restrict__ Ah, const unsigned short* __restrict__ Al,
    const unsigned short* __restrict__ Bh, const unsigned short* __restrict__ Bl,
    const float* __restrict__ bias,
    float* __restrict__ Cf, unsigned short* __restrict__ ChO, unsigned short* __restrict__ ClO,
    int M, int K, int N)
{
    __shared__ __align__(16) short lds[4][128][32];   // Ah, Al, Bh, Bl tiles: 32 KB

    const int tid = threadIdx.x;
    const int w   = tid >> 6;
    const int l   = tid & 63;
    const int l16 = l & 15;
    const int lq  = l >> 4;
    const int bm  = blockIdx.y * 128;
    const int bn  = blockIdx.x * 128;
    const int wm  = (w & 1) * 64;
    const int wn  = (w >> 1) * 64;

    f32x4 acc[4][4];
    #pragma unroll
    for (int i = 0; i < 4; ++i)
        #pragma unroll
        for (int j = 0; j < 4; ++j)
            acc[i][j] = (f32x4){0.f, 0.f, 0.f, 0.f};

    const int jrow = l >> 2;   // 0..15
    const int jkc  = l & 3;    // 0..3

    for (int k0 = 0; k0 < K; k0 += 32) {
        #pragma unroll
        for (int j = 0; j < 2; ++j) {
            int t = w * 2 + j;                    // instr index 0..7
            int r = t * 16 + jrow;                // tile row 0..127
            size_t goffA = (size_t)(bm + r) * K + k0 + jkc * 8;
            size_t goffB = (size_t)(bn + r) * K + k0 + jkc * 8;
            short* base0 = &lds[0][0][0] + t * 512;   // wave-uniform LDS base
            short* base1 = &lds[1][0][0] + t * 512;
            short* base2 = &lds[2][0][0] + t * 512;
            short* base3 = &lds[3][0][0] + t * 512;
            stage16(Ah + goffA, base0);
            stage16(Al + goffA, base1);
            stage16(Bh + goffB, base2);
            stage16(Bl + goffB, base3);
        }
        __syncthreads();

        bf16x8 ah[4], al[4], bh[4], bl[4];
        #pragma unroll
        for (int i = 0; i < 4; ++i) {
            ah[i] = *(const bf16x8*)&lds[0][wm + i*16 + l16][lq*8];
            al[i] = *(const bf16x8*)&lds[1][wm + i*16 + l16][lq*8];
            bh[i] = *(const bf16x8*)&lds[2][wn + i*16 + l16][lq*8];
            bl[i] = *(const bf16x8*)&lds[3][wn + i*16 + l16][lq*8];
        }
        #pragma unroll
        for (int i = 0; i < 4; ++i)
            #pragma unroll
            for (int j = 0; j < 4; ++j) {
                acc[i][j] = __builtin_amdgcn_mfma_f32_16x16x32_bf16(ah[i], bh[j], acc[i][j], 0, 0, 0);
                acc[i][j] = __builtin_amdgcn_mfma_f32_16x16x32_bf16(ah[i], bl[j], acc[i][j], 0, 0, 0);
                acc[i][j] = __builtin_amdgcn_mfma_f32_16x16x32_bf16(al[i], bh[j], acc[i][j], 0, 0, 0);
            }
        __syncthreads();
    }

    // epilogue: C/D layout col=lane&15, row=(lane>>4)*4+reg
    #pragma unroll
    for (int j = 0; j < 4; ++j) {
        int n = bn + wn + j * 16 + l16;
        float bv = bias[n];
        #pragma unroll
        for (int i = 0; i < 4; ++i) {
            int mrow = bm + wm + i * 16 + lq * 4;
            #pragma unroll
            for (int r = 0; r < 4; ++r) {
                float v = acc[i][j][r] + bv;
                if (ACT) v = gelu_f(v);
                size_t off = (size_t)(mrow + r) * N + n;
                if (OUT_MODE == 0) {
                    Cf[off] = v;
                } else {
                    unsigned short h = f2bf(v);
                    ChO[off] = h;
                    ClO[off] = f2bf(v - bf2f(h));
                }
            }
        }
    }
}

// ---------------------------------------------------------------------------
// segment mean over sorted qidx -> bf16 hi/lo mean
// ---------------------------------------------------------------------------
__global__ __launch_bounds__(128) void seg_mean(
    const int* __restrict__ edges, const float* __restrict__ h2,
    unsigned short* __restrict__ mH, unsigned short* __restrict__ mL)
{
    const int q = blockIdx.x;
    const int t = threadIdx.x;

    int lo = 0, hi = NE_;
    while (lo < hi) { int mid = (lo + hi) >> 1; if (edges[2 * mid] < q) lo = mid + 1; else hi = mid; }
    const int s = lo;
    hi = NE_;
    while (lo < hi) { int mid = (lo + hi) >> 1; if (edges[2 * mid] < q + 1) lo = mid + 1; else hi = mid; }
    const int e_end = lo;

    float acc = 0.0f;
    for (int e = s; e < e_end; ++e) acc += h2[(size_t)e * BOT + t];
    int cnt = e_end - s;
    float m = acc / (float)(cnt > 0 ? cnt : 1);
    split_store(m, &mH[(size_t)q * BOT + t], &mL[(size_t)q * BOT + t]);
}

// ---------------------------------------------------------------------------
// out[NQ,4] = g1[NQ,256] @ pw1[256,4] + pb1 : one wave per row
// ---------------------------------------------------------------------------
__global__ __launch_bounds__(256) void pred1_kernel(
    const float* __restrict__ g1, const float* __restrict__ w,
    const float* __restrict__ b, float* __restrict__ out)
{
    const int wave = threadIdx.x >> 6;
    const int lane = threadIdx.x & 63;
    const int row  = blockIdx.x * 4 + wave;

    const float* g = g1 + (size_t)row * 256;
    float a0 = 0, a1 = 0, a2 = 0, a3 = 0;
    #pragma unroll
    for (int i = 0; i < 4; ++i) {
        int k = lane + 64 * i;
        float gv = g[k];
        const float* wr = w + k * 4;
        a0 = fmaf(gv, wr[0], a0);
        a1 = fmaf(gv, wr[1], a1);
        a2 = fmaf(gv, wr[2], a2);
        a3 = fmaf(gv, wr[3], a3);
    }
    #pragma unroll
    for (int off = 32; off > 0; off >>= 1) {
        a0 += __shfl_down(a0, off, 64);
        a1 += __shfl_down(a1, off, 64);
        a2 += __shfl_down(a2, off, 64);
        a3 += __shfl_down(a3, off, 64);
    }
    if (lane == 0) {
        float4 o = {a0 + b[0], a1 + b[1], a2 + b[2], a3 + b[3]};
        *(float4*)&out[(size_t)row * 4] = o;
    }
}

// ---------------------------------------------------------------------------
extern "C" void kernel_launch(void* const* d_in, const int* in_sizes, int n_in,
                              void* d_out, int out_size, void* d_ws, size_t ws_size,
                              hipStream_t stream)
{
    const float* x    = (const float*)d_in[0];
    const float* qpos = (const float*)d_in[1];
    const int*   edges= (const int*)  d_in[2];
    const float* w0   = (const float*)d_in[3];
    const float* b0   = (const float*)d_in[4];
    const float* w1   = (const float*)d_in[5];
    const float* b1   = (const float*)d_in[6];
    const float* w2   = (const float*)d_in[7];
    const float* b2   = (const float*)d_in[8];
    const float* pw0  = (const float*)d_in[9];
    const float* pb0  = (const float*)d_in[10];
    const float* pw1  = (const float*)d_in[11];
    const float* pb1  = (const float*)d_in[12];
    float* out = (float*)d_out;

    char* ws = (char*)d_ws;
    unsigned short* featH = (unsigned short*)(ws + OFF_FEATH);
    unsigned short* featL = (unsigned short*)(ws + OFF_FEATL);
    unsigned short* h0H   = (unsigned short*)(ws + OFF_H0H);
    unsigned short* h0L   = (unsigned short*)(ws + OFF_H0L);
    unsigned short* h1H   = (unsigned short*)(ws + OFF_H1H);
    unsigned short* h1L   = (unsigned short*)(ws + OFF_H1L);
    unsigned short* w0H   = (unsigned short*)(ws + OFF_W0H);
    unsigned short* w0L   = (unsigned short*)(ws + OFF_W0L);
    unsigned short* w1H   = (unsigned short*)(ws + OFF_W1H);
    unsigned short* w1L   = (unsigned short*)(ws + OFF_W1L);
    unsigned short* w2H   = (unsigned short*)(ws + OFF_W2H);
    unsigned short* w2L   = (unsigned short*)(ws + OFF_W2L);
    unsigned short* pw0H  = (unsigned short*)(ws + OFF_PW0H);
    unsigned short* pw0L  = (unsigned short*)(ws + OFF_PW0L);
    float*          h2    = (float*)(ws + OFF_H2);
    unsigned short* meanH = (unsigned short*)(ws + OFF_MEANH);
    unsigned short* meanL = (unsigned short*)(ws + OFF_MEANL);
    float*          g1    = (float*)(ws + OFF_G1);

    // weight conversion (transposed hi/lo bf16)
    conv_w<<<(FEAT_DIM*H0_DIM + 255)/256, 256, 0, stream>>>(w0, w0H, w0L, FEAT_DIM, H0_DIM);
    conv_w<<<(H0_DIM*H1_DIM + 255)/256, 256, 0, stream>>>(w1, w1H, w1L, H0_DIM, H1_DIM);
    conv_w<<<(H1_DIM*BOT + 255)/256, 256, 0, stream>>>(w2, w2H, w2L, H1_DIM, BOT);
    conv_w<<<(BOT*H1_DIM + 255)/256, 256, 0, stream>>>(pw0, pw0H, pw0L, BOT, H1_DIM);

    for (int c = 0; c < NCHUNK; ++c) {
        const int ebase = c * CH;
        build_feat<<<CH, 256, 0, stream>>>(x, qpos, edges, featH, featL, ebase);
        gemm_mfma<1, 1><<<dim3(H0_DIM/128, CH/128), 256, 0, stream>>>(
            featH, featL, w0H, w0L, b0, nullptr, h0H, h0L, CH, FEAT_DIM, H0_DIM);
        gemm_mfma<1, 1><<<dim3(H1_DIM/128, CH/128), 256, 0, stream>>>(
            h0H, h0L, w1H, w1L, b1, nullptr, h1H, h1L, CH, H0_DIM, H1_DIM);
        gemm_mfma<0, 0><<<dim3(BOT/128, CH/128), 256, 0, stream>>>(
            h1H, h1L, w2H, w2L, b2, h2 + (size_t)ebase * BOT, nullptr, nullptr, CH, H1_DIM, BOT);
    }

    seg_mean<<<NQ_, 128, 0, stream>>>(edges, h2, meanH, meanL);
    gemm_mfma<1, 0><<<dim3(H1_DIM/128, NQ_/128), 256, 0, stream>>>(
        meanH, meanL, pw0H, pw0L, pb0, g1, nullptr, nullptr, NQ_, BOT, H1_DIM);
    pred1_kernel<<<NQ_/4, 256, 0, stream>>>(g1, pw1, pb1, out);
}

// Round 3
// 2394.748 us; speedup vs baseline: 1.9314x; 1.1216x over previous
//
#include <hip/hip_runtime.h>
#include <cmath>

// Problem constants
#define IN_DIM   256
#define PE_DIM   512
#define FEAT_DIM 768
#define H0_DIM   512
#define H1_DIM   256
#define BOT      128
#define NQ_      131072
#define NE_      262144
#define CH       16384
#define NCHUNK   (NE_/CH)

// Workspace layout (bytes), total 320 MB.
static const size_t OFF_FEATH = 0;
static const size_t OFF_FEATL = 25165824;
static const size_t OFF_H0H   = 50331648;
static const size_t OFF_H0L   = 67108864;
static const size_t OFF_H1H   = 83886080;
static const size_t OFF_H1L   = 92274688;
static const size_t OFF_W0H   = 100663296;
static const size_t OFF_W0L   = 101449728;
static const size_t OFF_W1H   = 102236160;
static const size_t OFF_W1L   = 102498304;
static const size_t OFF_W2H   = 102760448;
static const size_t OFF_W2L   = 102825984;
static const size_t OFF_PW0H  = 102891520;
static const size_t OFF_PW0L  = 102957056;
static const size_t OFF_START = 103022592;   // (NQ+1)*4 = 512 KB
static const size_t OFF_H2    = 201326592;   // 128 MB (E*128*4)
static const size_t OFF_MEANH = 0;
static const size_t OFF_MEANL = 33554432;
static const size_t OFF_G1    = 201326592;   // reuses h2 (dead after seg_mean)

typedef __attribute__((ext_vector_type(8))) short bf16x8;
typedef __attribute__((ext_vector_type(4))) float f32x4;

__device__ __forceinline__ float gelu_f(float v) {
    return v * 0.5f * (1.0f + erff(v * 0.7071067811865476f));
}
__device__ __forceinline__ unsigned short f2bf(float f) {
    unsigned int u = __float_as_uint(f);
    unsigned int r = (u + 0x7FFFu + ((u >> 16) & 1u)) >> 16;
    return (unsigned short)r;
}
__device__ __forceinline__ float bf2f(unsigned short h) {
    return __uint_as_float(((unsigned int)h) << 16);
}
__device__ __forceinline__ void split_store(float v, unsigned short* ph, unsigned short* pl) {
    unsigned short h = f2bf(v);
    *ph = h;
    *pl = f2bf(v - bf2f(h));
}
__device__ __forceinline__ unsigned int pack2(unsigned short a, unsigned short b) {
    return (unsigned int)a | ((unsigned int)b << 16);
}
__device__ __forceinline__ void stage16(const void* g, void* l) {
    __builtin_amdgcn_global_load_lds(
        (const __attribute__((address_space(1))) unsigned int*)g,
        (__attribute__((address_space(3))) unsigned int*)l,
        16, 0, 0);
}

// ---------------------------------------------------------------------------
// Weight convert: W[K][N] fp32 -> WT hi/lo bf16 [N][K]
// ---------------------------------------------------------------------------
__global__ __launch_bounds__(256) void conv_w(
    const float* __restrict__ W, unsigned short* __restrict__ WTh,
    unsigned short* __restrict__ WTl, int K, int N)
{
    int idx = blockIdx.x * 256 + threadIdx.x;
    if (idx >= K * N) return;
    int k = idx / N, n = idx % N;
    float v = W[idx];
    unsigned short h = f2bf(v);
    WTh[(size_t)n * K + k] = h;
    WTl[(size_t)n * K + k] = f2bf(v - bf2f(h));
}

// ---------------------------------------------------------------------------
// Segment start offsets: start[q] = first edge index with qidx >= q.
// Thread per edge (plus one tail thread). qidx sorted ascending.
// ---------------------------------------------------------------------------
__global__ __launch_bounds__(256) void seg_offsets(
    const int* __restrict__ edges, int* __restrict__ start)
{
    int e = blockIdx.x * 256 + threadIdx.x;
    if (e > NE_) return;
    int qc = (e < NE_) ? edges[2 * e] : NQ_;
    int qp = (e > 0) ? edges[2 * e - 2] : -1;
    for (int q = qp + 1; q <= qc; ++q) start[q] = e;
}

// ---------------------------------------------------------------------------
// feat build -> bf16 hi/lo [CH][768]; one wave per edge (4 edges / block)
// ---------------------------------------------------------------------------
__global__ __launch_bounds__(256) void build_feat(
    const float* __restrict__ x, const float* __restrict__ qpos,
    const int* __restrict__ edges,
    unsigned short* __restrict__ fH, unsigned short* __restrict__ fL, int ebase)
{
    const int wv = threadIdx.x >> 6;
    const int l  = threadIdx.x & 63;
    const int le = blockIdx.x * 4 + wv;
    const int e  = ebase + le;
    const int q  = edges[2 * e];
    const int g  = edges[2 * e + 1];
    const size_t base = (size_t)le * FEAT_DIM;

    // x part: 4 consecutive cols per lane
    {
        float4 v = *(const float4*)&x[(size_t)g * IN_DIM + l * 4];
        unsigned short h0 = f2bf(v.x), h1 = f2bf(v.y), h2 = f2bf(v.z), h3 = f2bf(v.w);
        uint2 H, L;
        H.x = pack2(h0, h1); H.y = pack2(h2, h3);
        L.x = pack2(f2bf(v.x - bf2f(h0)), f2bf(v.y - bf2f(h1)));
        L.y = pack2(f2bf(v.z - bf2f(h2)), f2bf(v.w - bf2f(h3)));
        *(uint2*)&fH[base + l * 4] = H;
        *(uint2*)&fL[base + l * 4] = L;
    }
    // PE part: 8 consecutive elems per lane (same coord & same sin/cos half)
    {
        const int i0 = l * 8;            // 0..504
        const int c  = i0 >> 7;          // coord 0..3
        const int j0 = i0 & 127;
        const float cv = (c < 3) ? (qpos[q * 3 + c] * 0.01f - 1.0f) : 1.0f;
        const bool is_sin = (j0 < 64);
        const int jj0 = j0 & 63;
        unsigned int hw[4], lw[4];
        #pragma unroll
        for (int p2 = 0; p2 < 4; ++p2) {
            unsigned short hh[2], ll[2];
            #pragma unroll
            for (int s = 0; s < 2; ++s) {
                int jj = jj0 + p2 * 2 + s;
                float om  = exp2f((float)jj * (-13.287712379549449f / 64.0f));
                float arg = cv * om;
                float v   = is_sin ? __sinf(arg) : __cosf(arg);
                unsigned short h = f2bf(v);
                hh[s] = h; ll[s] = f2bf(v - bf2f(h));
            }
            hw[p2] = pack2(hh[0], hh[1]);
            lw[p2] = pack2(ll[0], ll[1]);
        }
        uint4 H, L;
        H.x = hw[0]; H.y = hw[1]; H.z = hw[2]; H.w = hw[3];
        L.x = lw[0]; L.y = lw[1]; L.z = lw[2]; L.w = lw[3];
        *(uint4*)&fH[base + IN_DIM + i0] = H;
        *(uint4*)&fL[base + IN_DIM + i0] = L;
    }
}

// ---------------------------------------------------------------------------
// Split-bf16 MFMA GEMM (3 passes AhBh+AhBl+AlBh). 128x128 tile, BK=32.
// OUT_MODE 0: fp32 direct store. OUT_MODE 1: bf16 hi/lo via LDS transpose
// (XOR-swizzled) so stores are 16B row-major vectors.
// ---------------------------------------------------------------------------
template <int ACT, int OUT_MODE>
__global__ __launch_bounds__(256) void gemm_mfma(
    const unsigned short* __restrict__ Ah, const unsigned short* __restrict__ Al,
    const unsigned short* __restrict__ Bh, const unsigned short* __restrict__ Bl,
    const float* __restrict__ bias,
    float* __restrict__ Cf, unsigned short* __restrict__ ChO, unsigned short* __restrict__ ClO,
    int M, int K, int N)
{
    __shared__ __align__(16) short lds[4][128][32];   // 32 KB

    const int tid = threadIdx.x;
    const int w   = tid >> 6;
    const int l   = tid & 63;
    const int l16 = l & 15;
    const int lq  = l >> 4;
    const int bm  = blockIdx.y * 128;
    const int bn  = blockIdx.x * 128;
    const int wm  = (w & 1) * 64;
    const int wn  = (w >> 1) * 64;

    f32x4 acc[4][4];
    #pragma unroll
    for (int i = 0; i < 4; ++i)
        #pragma unroll
        for (int j = 0; j < 4; ++j)
            acc[i][j] = (f32x4){0.f, 0.f, 0.f, 0.f};

    const int jrow = l >> 2;
    const int jkc  = l & 3;

    for (int k0 = 0; k0 < K; k0 += 32) {
        #pragma unroll
        for (int j = 0; j < 2; ++j) {
            int t = w * 2 + j;
            int r = t * 16 + jrow;
            size_t goffA = (size_t)(bm + r) * K + k0 + jkc * 8;
            size_t goffB = (size_t)(bn + r) * K + k0 + jkc * 8;
            short* base0 = &lds[0][0][0] + t * 512;
            short* base1 = &lds[1][0][0] + t * 512;
            short* base2 = &lds[2][0][0] + t * 512;
            short* base3 = &lds[3][0][0] + t * 512;
            stage16(Ah + goffA, base0);
            stage16(Al + goffA, base1);
            stage16(Bh + goffB, base2);
            stage16(Bl + goffB, base3);
        }
        __syncthreads();

        bf16x8 ah[4], al[4], bh[4], bl[4];
        #pragma unroll
        for (int i = 0; i < 4; ++i) {
            ah[i] = *(const bf16x8*)&lds[0][wm + i*16 + l16][lq*8];
            al[i] = *(const bf16x8*)&lds[1][wm + i*16 + l16][lq*8];
            bh[i] = *(const bf16x8*)&lds[2][wn + i*16 + l16][lq*8];
            bl[i] = *(const bf16x8*)&lds[3][wn + i*16 + l16][lq*8];
        }
        #pragma unroll
        for (int i = 0; i < 4; ++i)
            #pragma unroll
            for (int j = 0; j < 4; ++j) {
                acc[i][j] = __builtin_amdgcn_mfma_f32_16x16x32_bf16(ah[i], bh[j], acc[i][j], 0, 0, 0);
                acc[i][j] = __builtin_amdgcn_mfma_f32_16x16x32_bf16(ah[i], bl[j], acc[i][j], 0, 0, 0);
                acc[i][j] = __builtin_amdgcn_mfma_f32_16x16x32_bf16(al[i], bh[j], acc[i][j], 0, 0, 0);
            }
        __syncthreads();
    }

    if (OUT_MODE == 0) {
        // direct fp32 stores (4B, 64B segments per 16 lanes)
        #pragma unroll
        for (int j = 0; j < 4; ++j) {
            int n = bn + wn + j * 16 + l16;
            float bv = bias[n];
            #pragma unroll
            for (int i = 0; i < 4; ++i) {
                int mrow = bm + wm + i * 16 + lq * 4;
                #pragma unroll
                for (int r = 0; r < 4; ++r) {
                    float v = acc[i][j][r] + bv;
                    if (ACT) v = gelu_f(v);
                    Cf[(size_t)(mrow + r) * N + n] = v;
                }
            }
        }
    } else {
        // bf16 hi/lo via XOR-swizzled LDS transpose: each lane then owns a
        // full 32-col row segment -> 16B vector stores.
        float* lbuf = ((float*)&lds[0][0][0]) + w * 2048;   // 8KB per wave
        #pragma unroll
        for (int h = 0; h < 2; ++h) {
            #pragma unroll
            for (int j2 = 0; j2 < 2; ++j2) {
                int j = 2 * h + j2;
                float bv = bias[bn + wn + j * 16 + l16];
                #pragma unroll
                for (int i = 0; i < 4; ++i) {
                    #pragma unroll
                    for (int r = 0; r < 4; ++r) {
                        int rowq = i * 16 + lq * 4 + r;          // 0..63
                        int col  = j2 * 16 + l16;                // 0..31
                        int quad = col >> 2, wi = col & 3;
                        float v = acc[i][j][r] + bv;
                        if (ACT) v = gelu_f(v);
                        lbuf[rowq * 32 + ((quad ^ (rowq & 7)) << 2) + wi] = v;
                    }
                }
            }
            __syncthreads();
            {
                const size_t grow = (size_t)(bm + wm + l);
                unsigned short* ph = ChO + grow * N + bn + wn + h * 32;
                unsigned short* pl = ClO + grow * N + bn + wn + h * 32;
                #pragma unroll
                for (int cc = 0; cc < 4; ++cc) {       // 4x (8 cols -> uint4)
                    unsigned int hw[4], lw[4];
                    #pragma unroll
                    for (int c2 = 0; c2 < 2; ++c2) {
                        int cq = cc * 2 + c2;
                        float4 v = *(const float4*)&lbuf[l * 32 + ((cq ^ (l & 7)) << 2)];
                        unsigned short ha = f2bf(v.x), hb = f2bf(v.y);
                        unsigned short hc = f2bf(v.z), hd = f2bf(v.w);
                        hw[c2*2+0] = pack2(ha, hb);
                        hw[c2*2+1] = pack2(hc, hd);
                        lw[c2*2+0] = pack2(f2bf(v.x - bf2f(ha)), f2bf(v.y - bf2f(hb)));
                        lw[c2*2+1] = pack2(f2bf(v.z - bf2f(hc)), f2bf(v.w - bf2f(hd)));
                    }
                    uint4 H, L;
                    H.x = hw[0]; H.y = hw[1]; H.z = hw[2]; H.w = hw[3];
                    L.x = lw[0]; L.y = lw[1]; L.z = lw[2]; L.w = lw[3];
                    *(uint4*)&ph[cc * 8] = H;
                    *(uint4*)&pl[cc * 8] = L;
                }
            }
            __syncthreads();
        }
    }
}

// ---------------------------------------------------------------------------
// segment mean via precomputed offsets: 8 queries per block, float4 loads,
// packed ushort4 hi/lo stores.
// ---------------------------------------------------------------------------
__global__ __launch_bounds__(256) void seg_mean(
    const int* __restrict__ start, const float* __restrict__ h2,
    unsigned short* __restrict__ mH, unsigned short* __restrict__ mL)
{
    const int t = threadIdx.x;
    const int q = blockIdx.x * 8 + (t >> 5);
    const int quad = t & 31;
    const int s = start[q];
    const int e = start[q + 1];

    float4 acc = make_float4(0.f, 0.f, 0.f, 0.f);
    for (int i = s; i < e; ++i) {
        const float4 v = *(const float4*)&h2[(size_t)i * BOT + quad * 4];
        acc.x += v.x; acc.y += v.y; acc.z += v.z; acc.w += v.w;
    }
    const float inv = 1.0f / (float)((e - s) > 0 ? (e - s) : 1);
    float m0 = acc.x * inv, m1 = acc.y * inv, m2 = acc.z * inv, m3 = acc.w * inv;
    unsigned short h0 = f2bf(m0), h1 = f2bf(m1), h2s = f2bf(m2), h3 = f2bf(m3);
    uint2 H, L;
    H.x = pack2(h0, h1); H.y = pack2(h2s, h3);
    L.x = pack2(f2bf(m0 - bf2f(h0)), f2bf(m1 - bf2f(h1)));
    L.y = pack2(f2bf(m2 - bf2f(h2s)), f2bf(m3 - bf2f(h3)));
    *(uint2*)&mH[(size_t)q * BOT + quad * 4] = H;
    *(uint2*)&mL[(size_t)q * BOT + quad * 4] = L;
}

// ---------------------------------------------------------------------------
// out[NQ,4] = g1[NQ,256] @ pw1[256,4] + pb1 : one wave per row
// ---------------------------------------------------------------------------
__global__ __launch_bounds__(256) void pred1_kernel(
    const float* __restrict__ g1, const float* __restrict__ w,
    const float* __restrict__ b, float* __restrict__ out)
{
    const int wave = threadIdx.x >> 6;
    const int lane = threadIdx.x & 63;
    const int row  = blockIdx.x * 4 + wave;

    const float* g = g1 + (size_t)row * 256;
    float a0 = 0, a1 = 0, a2 = 0, a3 = 0;
    #pragma unroll
    for (int i = 0; i < 4; ++i) {
        int k = lane + 64 * i;
        float gv = g[k];
        const float* wr = w + k * 4;
        a0 = fmaf(gv, wr[0], a0);
        a1 = fmaf(gv, wr[1], a1);
        a2 = fmaf(gv, wr[2], a2);
        a3 = fmaf(gv, wr[3], a3);
    }
    #pragma unroll
    for (int off = 32; off > 0; off >>= 1) {
        a0 += __shfl_down(a0, off, 64);
        a1 += __shfl_down(a1, off, 64);
        a2 += __shfl_down(a2, off, 64);
        a3 += __shfl_down(a3, off, 64);
    }
    if (lane == 0) {
        float4 o = {a0 + b[0], a1 + b[1], a2 + b[2], a3 + b[3]};
        *(float4*)&out[(size_t)row * 4] = o;
    }
}

// ---------------------------------------------------------------------------
extern "C" void kernel_launch(void* const* d_in, const int* in_sizes, int n_in,
                              void* d_out, int out_size, void* d_ws, size_t ws_size,
                              hipStream_t stream)
{
    const float* x    = (const float*)d_in[0];
    const float* qpos = (const float*)d_in[1];
    const int*   edges= (const int*)  d_in[2];
    const float* w0   = (const float*)d_in[3];
    const float* b0   = (const float*)d_in[4];
    const float* w1   = (const float*)d_in[5];
    const float* b1   = (const float*)d_in[6];
    const float* w2   = (const float*)d_in[7];
    const float* b2   = (const float*)d_in[8];
    const float* pw0  = (const float*)d_in[9];
    const float* pb0  = (const float*)d_in[10];
    const float* pw1  = (const float*)d_in[11];
    const float* pb1  = (const float*)d_in[12];
    float* out = (float*)d_out;

    char* ws = (char*)d_ws;
    unsigned short* featH = (unsigned short*)(ws + OFF_FEATH);
    unsigned short* featL = (unsigned short*)(ws + OFF_FEATL);
    unsigned short* h0H   = (unsigned short*)(ws + OFF_H0H);
    unsigned short* h0L   = (unsigned short*)(ws + OFF_H0L);
    unsigned short* h1H   = (unsigned short*)(ws + OFF_H1H);
    unsigned short* h1L   = (unsigned short*)(ws + OFF_H1L);
    unsigned short* w0H   = (unsigned short*)(ws + OFF_W0H);
    unsigned short* w0L   = (unsigned short*)(ws + OFF_W0L);
    unsigned short* w1H   = (unsigned short*)(ws + OFF_W1H);
    unsigned short* w1L   = (unsigned short*)(ws + OFF_W1L);
    unsigned short* w2H   = (unsigned short*)(ws + OFF_W2H);
    unsigned short* w2L   = (unsigned short*)(ws + OFF_W2L);
    unsigned short* pw0H  = (unsigned short*)(ws + OFF_PW0H);
    unsigned short* pw0L  = (unsigned short*)(ws + OFF_PW0L);
    int*            start = (int*)(ws + OFF_START);
    float*          h2    = (float*)(ws + OFF_H2);
    unsigned short* meanH = (unsigned short*)(ws + OFF_MEANH);
    unsigned short* meanL = (unsigned short*)(ws + OFF_MEANL);
    float*          g1    = (float*)(ws + OFF_G1);

    conv_w<<<(FEAT_DIM*H0_DIM + 255)/256, 256, 0, stream>>>(w0, w0H, w0L, FEAT_DIM, H0_DIM);
    conv_w<<<(H0_DIM*H1_DIM + 255)/256, 256, 0, stream>>>(w1, w1H, w1L, H0_DIM, H1_DIM);
    conv_w<<<(H1_DIM*BOT + 255)/256, 256, 0, stream>>>(w2, w2H, w2L, H1_DIM, BOT);
    conv_w<<<(BOT*H1_DIM + 255)/256, 256, 0, stream>>>(pw0, pw0H, pw0L, BOT, H1_DIM);
    seg_offsets<<<(NE_ + 1 + 255)/256, 256, 0, stream>>>(edges, start);

    for (int c = 0; c < NCHUNK; ++c) {
        const int ebase = c * CH;
        build_feat<<<CH/4, 256, 0, stream>>>(x, qpos, edges, featH, featL, ebase);
        gemm_mfma<1, 1><<<dim3(H0_DIM/128, CH/128), 256, 0, stream>>>(
            featH, featL, w0H, w0L, b0, nullptr, h0H, h0L, CH, FEAT_DIM, H0_DIM);
        gemm_mfma<1, 1><<<dim3(H1_DIM/128, CH/128), 256, 0, stream>>>(
            h0H, h0L, w1H, w1L, b1, nullptr, h1H, h1L, CH, H0_DIM, H1_DIM);
        gemm_mfma<0, 0><<<dim3(BOT/128, CH/128), 256, 0, stream>>>(
            h1H, h1L, w2H, w2L, b2, h2 + (size_t)ebase * BOT, nullptr, nullptr, CH, H1_DIM, BOT);
    }

    seg_mean<<<NQ_/8, 256, 0, stream>>>(start, h2, meanH, meanL);
    gemm_mfma<1, 0><<<dim3(H1_DIM/128, NQ_/128), 256, 0, stream>>>(
        meanH, meanL, pw0H, pw0L, pb0, g1, nullptr, nullptr, NQ_, BOT, H1_DIM);
    pred1_kernel<<<NQ_/4, 256, 0, stream>>>(g1, pw1, pb1, out);
}

// Round 4
// 2276.636 us; speedup vs baseline: 2.0316x; 1.0519x over previous
//
#include <hip/hip_runtime.h>
#include <cmath>

// Problem constants
#define IN_DIM   256
#define H0_DIM   512
#define H1_DIM   256
#define BOT      128
#define NQ_      131072
#define NE_      262144
#define CH       32768
#define NCHUNK   (NE_/CH)
#define ZWIN     18432       // query window rows per chunk (covers ~16384 +/- 12 sigma)

// Workspace layout (bytes), total ~309 MB (phase-aliased).
static const size_t OFF_ZWIN  = 0;            // 18432*512*4 = 37748736
static const size_t OFF_FXH   = 37748736;     // 32768*256*2
static const size_t OFF_FXL   = 54525952;
static const size_t OFF_PEH   = 37748736;     // alias FXH/FXL (+h0 head), phase-safe
static const size_t OFF_PEL   = 56623104;
static const size_t OFF_H0H   = 71303168;     // 32768*512*2
static const size_t OFF_H0L   = 104857600;
static const size_t OFF_H1H   = 138412032;    // 32768*256*2
static const size_t OFF_H1L   = 155189248;
static const size_t OFF_H2    = 171966464;    // NE*128*4 = 134217728
static const size_t OFF_W0AH  = 306184192;
static const size_t OFF_W0AL  = 306446336;
static const size_t OFF_W0BH  = 306708480;
static const size_t OFF_W0BL  = 307232768;
static const size_t OFF_W1H   = 307757056;
static const size_t OFF_W1L   = 308019200;
static const size_t OFF_W2H   = 308281344;
static const size_t OFF_W2L   = 308346880;
static const size_t OFF_PW0H  = 308412416;
static const size_t OFF_PW0L  = 308477952;
static const size_t OFF_START = 308543488;    // (NQ+1)*4
static const size_t OFF_WINLO = 309067780;    // 8*4
// post-loop aliases (h2 dead after seg_mean; Zwin/featx dead after loop)
static const size_t OFF_MEANH = 0;
static const size_t OFF_MEANL = 33554432;
static const size_t OFF_G1    = 71303168;

typedef __attribute__((ext_vector_type(8))) short bf16x8;
typedef __attribute__((ext_vector_type(4))) float f32x4;

__device__ __forceinline__ float gelu_f(float v) {
    return v * 0.5f * (1.0f + erff(v * 0.7071067811865476f));
}
__device__ __forceinline__ unsigned short f2bf(float f) {
    unsigned int u = __float_as_uint(f);
    unsigned int r = (u + 0x7FFFu + ((u >> 16) & 1u)) >> 16;
    return (unsigned short)r;
}
__device__ __forceinline__ float bf2f(unsigned short h) {
    return __uint_as_float(((unsigned int)h) << 16);
}
__device__ __forceinline__ unsigned int pack2(unsigned short a, unsigned short b) {
    return (unsigned int)a | ((unsigned int)b << 16);
}
__device__ __forceinline__ void stage16(const void* g, void* l) {
    __builtin_amdgcn_global_load_lds(
        (const __attribute__((address_space(1))) unsigned int*)g,
        (__attribute__((address_space(3))) unsigned int*)l,
        16, 0, 0);
}

// ---------------------------------------------------------------------------
// Weight convert: W[K][N] fp32 -> WT hi/lo bf16 [N][K]
// ---------------------------------------------------------------------------
__global__ __launch_bounds__(256) void conv_w(
    const float* __restrict__ W, unsigned short* __restrict__ WTh,
    unsigned short* __restrict__ WTl, int K, int N)
{
    int idx = blockIdx.x * 256 + threadIdx.x;
    if (idx >= K * N) return;
    int k = idx / N, n = idx % N;
    float v = W[idx];
    unsigned short h = f2bf(v);
    WTh[(size_t)n * K + k] = h;
    WTl[(size_t)n * K + k] = f2bf(v - bf2f(h));
}

// ---------------------------------------------------------------------------
// start[q] = first edge index with qidx >= q (qidx sorted ascending)
// ---------------------------------------------------------------------------
__global__ __launch_bounds__(256) void seg_offsets(
    const int* __restrict__ edges, int* __restrict__ start)
{
    int e = blockIdx.x * 256 + threadIdx.x;
    if (e > NE_) return;
    int qc = (e < NE_) ? edges[2 * e] : NQ_;
    int qp = (e > 0) ? edges[2 * e - 2] : -1;
    for (int q = qp + 1; q <= qc; ++q) start[q] = e;
}

// winlo[c] = qidx of first edge of chunk c
__global__ void calc_winlo(const int* __restrict__ edges, int* __restrict__ winlo)
{
    int c = threadIdx.x;
    if (c < NCHUNK) winlo[c] = edges[2 * (c * CH)];
}

// ---------------------------------------------------------------------------
// PE build for window c: rows i in [0,ZWIN), query q = winlo[c]+i.
// One wave per row (8 consecutive elems per lane).
// ---------------------------------------------------------------------------
__global__ __launch_bounds__(256) void build_pe(
    const float* __restrict__ qpos, const int* __restrict__ winlo, int c,
    unsigned short* __restrict__ peH, unsigned short* __restrict__ peL)
{
    const int wv = threadIdx.x >> 6;
    const int l  = threadIdx.x & 63;
    const int i  = blockIdx.x * 4 + wv;
    const int q  = winlo[c] + i;
    const size_t base = (size_t)i * 512;

    const int i0 = l * 8;
    const int cc = i0 >> 7;
    const int j0 = i0 & 127;
    float cv = 0.0f;
    if (q < NQ_) cv = (cc < 3) ? (qpos[q * 3 + cc] * 0.01f - 1.0f) : 1.0f;
    const bool is_sin = (j0 < 64);
    const int jj0 = j0 & 63;
    unsigned int hw[4], lw[4];
    #pragma unroll
    for (int p2 = 0; p2 < 4; ++p2) {
        unsigned short hh[2], ll[2];
        #pragma unroll
        for (int s = 0; s < 2; ++s) {
            int jj = jj0 + p2 * 2 + s;
            float om  = exp2f((float)jj * (-13.287712379549449f / 64.0f));
            float arg = cv * om;
            float v   = is_sin ? __sinf(arg) : __cosf(arg);
            unsigned short h = f2bf(v);
            hh[s] = h; ll[s] = f2bf(v - bf2f(h));
        }
        hw[p2] = pack2(hh[0], hh[1]);
        lw[p2] = pack2(ll[0], ll[1]);
    }
    uint4 H, L;
    H.x = hw[0]; H.y = hw[1]; H.z = hw[2]; H.w = hw[3];
    L.x = lw[0]; L.y = lw[1]; L.z = lw[2]; L.w = lw[3];
    *(uint4*)&peH[base + i0] = H;
    *(uint4*)&peL[base + i0] = L;
}

// ---------------------------------------------------------------------------
// featx build: gather x rows -> bf16 hi/lo [CH][256]; one wave per edge
// ---------------------------------------------------------------------------
__global__ __launch_bounds__(256) void build_featx(
    const float* __restrict__ x, const int* __restrict__ edges,
    unsigned short* __restrict__ fH, unsigned short* __restrict__ fL, int ebase)
{
    const int wv = threadIdx.x >> 6;
    const int l  = threadIdx.x & 63;
    const int le = blockIdx.x * 4 + wv;
    const int g  = edges[2 * (ebase + le) + 1];
    const size_t base = (size_t)le * IN_DIM;

    float4 v = *(const float4*)&x[(size_t)g * IN_DIM + l * 4];
    unsigned short h0 = f2bf(v.x), h1 = f2bf(v.y), h2 = f2bf(v.z), h3 = f2bf(v.w);
    uint2 H, L;
    H.x = pack2(h0, h1); H.y = pack2(h2, h3);
    L.x = pack2(f2bf(v.x - bf2f(h0)), f2bf(v.y - bf2f(h1)));
    L.y = pack2(f2bf(v.z - bf2f(h2)), f2bf(v.w - bf2f(h3)));
    *(uint2*)&fH[base + l * 4] = H;
    *(uint2*)&fL[base + l * 4] = L;
}

// ---------------------------------------------------------------------------
// Split-bf16 MFMA GEMM (3 passes AhBh+AhBl+AlBh). 128x128 tile, BK=32.
// OUT_MODE 0: fp32 = acc + bias (ACT optional)
// OUT_MODE 1: bf16 hi/lo via XOR-swizzled LDS transpose (bias+ACT)
// OUT_MODE 2: bf16 hi/lo, val = gelu(acc + Zw[q - wl]), q from edges2 (no bias)
// ---------------------------------------------------------------------------
template <int ACT, int OUT_MODE>
__global__ __launch_bounds__(256) void gemm_mfma(
    const unsigned short* __restrict__ Ah, const unsigned short* __restrict__ Al,
    const unsigned short* __restrict__ Bh, const unsigned short* __restrict__ Bl,
    const float* __restrict__ bias,
    float* __restrict__ Cf, unsigned short* __restrict__ ChO, unsigned short* __restrict__ ClO,
    int M, int K, int N,
    const int* __restrict__ edges2, const float* __restrict__ Zw,
    const int* __restrict__ wlp)
{
    __shared__ __align__(16) short lds[4][128][32];   // 32 KB

    const int tid = threadIdx.x;
    const int w   = tid >> 6;
    const int l   = tid & 63;
    const int l16 = l & 15;
    const int lq  = l >> 4;
    const int bm  = blockIdx.y * 128;
    const int bn  = blockIdx.x * 128;
    const int wm  = (w & 1) * 64;
    const int wn  = (w >> 1) * 64;

    f32x4 acc[4][4];
    #pragma unroll
    for (int i = 0; i < 4; ++i)
        #pragma unroll
        for (int j = 0; j < 4; ++j)
            acc[i][j] = (f32x4){0.f, 0.f, 0.f, 0.f};

    const int jrow = l >> 2;
    const int jkc  = l & 3;

    for (int k0 = 0; k0 < K; k0 += 32) {
        #pragma unroll
        for (int j = 0; j < 2; ++j) {
            int t = w * 2 + j;
            int r = t * 16 + jrow;
            size_t goffA = (size_t)(bm + r) * K + k0 + jkc * 8;
            size_t goffB = (size_t)(bn + r) * K + k0 + jkc * 8;
            short* base0 = &lds[0][0][0] + t * 512;
            short* base1 = &lds[1][0][0] + t * 512;
            short* base2 = &lds[2][0][0] + t * 512;
            short* base3 = &lds[3][0][0] + t * 512;
            stage16(Ah + goffA, base0);
            stage16(Al + goffA, base1);
            stage16(Bh + goffB, base2);
            stage16(Bl + goffB, base3);
        }
        __syncthreads();

        bf16x8 ah[4], al[4], bh[4], bl[4];
        #pragma unroll
        for (int i = 0; i < 4; ++i) {
            ah[i] = *(const bf16x8*)&lds[0][wm + i*16 + l16][lq*8];
            al[i] = *(const bf16x8*)&lds[1][wm + i*16 + l16][lq*8];
            bh[i] = *(const bf16x8*)&lds[2][wn + i*16 + l16][lq*8];
            bl[i] = *(const bf16x8*)&lds[3][wn + i*16 + l16][lq*8];
        }
        #pragma unroll
        for (int i = 0; i < 4; ++i)
            #pragma unroll
            for (int j = 0; j < 4; ++j) {
                acc[i][j] = __builtin_amdgcn_mfma_f32_16x16x32_bf16(ah[i], bh[j], acc[i][j], 0, 0, 0);
                acc[i][j] = __builtin_amdgcn_mfma_f32_16x16x32_bf16(ah[i], bl[j], acc[i][j], 0, 0, 0);
                acc[i][j] = __builtin_amdgcn_mfma_f32_16x16x32_bf16(al[i], bh[j], acc[i][j], 0, 0, 0);
            }
        __syncthreads();
    }

    if (OUT_MODE == 0) {
        #pragma unroll
        for (int j = 0; j < 4; ++j) {
            int n = bn + wn + j * 16 + l16;
            float bv = bias[n];
            #pragma unroll
            for (int i = 0; i < 4; ++i) {
                int mrow = bm + wm + i * 16 + lq * 4;
                #pragma unroll
                for (int r = 0; r < 4; ++r) {
                    float v = acc[i][j][r] + bv;
                    if (ACT) v = gelu_f(v);
                    Cf[(size_t)(mrow + r) * N + n] = v;
                }
            }
        }
    } else if (OUT_MODE == 1) {
        // bf16 hi/lo via XOR-swizzled LDS transpose, bias+ACT at write
        float* lbuf = ((float*)&lds[0][0][0]) + w * 2048;
        #pragma unroll
        for (int h = 0; h < 2; ++h) {
            #pragma unroll
            for (int j2 = 0; j2 < 2; ++j2) {
                int j = 2 * h + j2;
                float bv = bias[bn + wn + j * 16 + l16];
                #pragma unroll
                for (int i = 0; i < 4; ++i) {
                    #pragma unroll
                    for (int r = 0; r < 4; ++r) {
                        int rowq = i * 16 + lq * 4 + r;
                        int col  = j2 * 16 + l16;
                        float v = acc[i][j][r] + bv;
                        if (ACT) v = gelu_f(v);
                        lbuf[rowq * 32 + (((col >> 2) ^ (rowq & 7)) << 2) + (col & 3)] = v;
                    }
                }
            }
            __syncthreads();
            {
                const size_t grow = (size_t)(bm + wm + l);
                unsigned short* ph = ChO + grow * N + bn + wn + h * 32;
                unsigned short* pl = ClO + grow * N + bn + wn + h * 32;
                #pragma unroll
                for (int cc = 0; cc < 4; ++cc) {
                    unsigned int hw[4], lw[4];
                    #pragma unroll
                    for (int c2 = 0; c2 < 2; ++c2) {
                        int cq = cc * 2 + c2;
                        float4 v = *(const float4*)&lbuf[l * 32 + ((cq ^ (l & 7)) << 2)];
                        unsigned short ha = f2bf(v.x), hb = f2bf(v.y);
                        unsigned short hc = f2bf(v.z), hd = f2bf(v.w);
                        hw[c2*2+0] = pack2(ha, hb);
                        hw[c2*2+1] = pack2(hc, hd);
                        lw[c2*2+0] = pack2(f2bf(v.x - bf2f(ha)), f2bf(v.y - bf2f(hb)));
                        lw[c2*2+1] = pack2(f2bf(v.z - bf2f(hc)), f2bf(v.w - bf2f(hd)));
                    }
                    uint4 H, L;
                    H.x = hw[0]; H.y = hw[1]; H.z = hw[2]; H.w = hw[3];
                    L.x = lw[0]; L.y = lw[1]; L.z = lw[2]; L.w = lw[3];
                    *(uint4*)&ph[cc * 8] = H;
                    *(uint4*)&pl[cc * 8] = L;
                }
            }
            __syncthreads();
        }
    } else {
        // OUT_MODE 2: raw transpose, then val = gelu(acc + Zw[q - wl][col])
        const int wl = wlp[0];
        const int q  = edges2[2 * (bm + wm + l)];
        float* lbuf = ((float*)&lds[0][0][0]) + w * 2048;
        #pragma unroll
        for (int h = 0; h < 2; ++h) {
            #pragma unroll
            for (int j2 = 0; j2 < 2; ++j2) {
                int j = 2 * h + j2;
                #pragma unroll
                for (int i = 0; i < 4; ++i) {
                    #pragma unroll
                    for (int r = 0; r < 4; ++r) {
                        int rowq = i * 16 + lq * 4 + r;
                        int col  = j2 * 16 + l16;
                        lbuf[rowq * 32 + (((col >> 2) ^ (rowq & 7)) << 2) + (col & 3)] = acc[i][j][r];
                    }
                }
            }
            __syncthreads();
            {
                const size_t grow = (size_t)(bm + wm + l);
                const float* zrow = Zw + (size_t)(q - wl) * H0_DIM + bn + wn + h * 32;
                unsigned short* ph = ChO + grow * N + bn + wn + h * 32;
                unsigned short* pl = ClO + grow * N + bn + wn + h * 32;
                #pragma unroll
                for (int cc = 0; cc < 4; ++cc) {
                    unsigned int hw[4], lw[4];
                    #pragma unroll
                    for (int c2 = 0; c2 < 2; ++c2) {
                        int cq = cc * 2 + c2;
                        float4 v = *(const float4*)&lbuf[l * 32 + ((cq ^ (l & 7)) << 2)];
                        float4 z = *(const float4*)&zrow[cq * 4];
                        v.x = gelu_f(v.x + z.x); v.y = gelu_f(v.y + z.y);
                        v.z = gelu_f(v.z + z.z); v.w = gelu_f(v.w + z.w);
                        unsigned short ha = f2bf(v.x), hb = f2bf(v.y);
                        unsigned short hc = f2bf(v.z), hd = f2bf(v.w);
                        hw[c2*2+0] = pack2(ha, hb);
                        hw[c2*2+1] = pack2(hc, hd);
                        lw[c2*2+0] = pack2(f2bf(v.x - bf2f(ha)), f2bf(v.y - bf2f(hb)));
                        lw[c2*2+1] = pack2(f2bf(v.z - bf2f(hc)), f2bf(v.w - bf2f(hd)));
                    }
                    uint4 H, L;
                    H.x = hw[0]; H.y = hw[1]; H.z = hw[2]; H.w = hw[3];
                    L.x = lw[0]; L.y = lw[1]; L.z = lw[2]; L.w = lw[3];
                    *(uint4*)&ph[cc * 8] = H;
                    *(uint4*)&pl[cc * 8] = L;
                }
            }
            __syncthreads();
        }
    }
}

// ---------------------------------------------------------------------------
// segment mean via precomputed offsets: 8 queries/block, float4 loads,
// packed hi/lo stores.
// ---------------------------------------------------------------------------
__global__ __launch_bounds__(256) void seg_mean(
    const int* __restrict__ start, const float* __restrict__ h2,
    unsigned short* __restrict__ mH, unsigned short* __restrict__ mL)
{
    const int t = threadIdx.x;
    const int q = blockIdx.x * 8 + (t >> 5);
    const int quad = t & 31;
    const int s = start[q];
    const int e = start[q + 1];

    float4 acc = make_float4(0.f, 0.f, 0.f, 0.f);
    for (int i = s; i < e; ++i) {
        const float4 v = *(const float4*)&h2[(size_t)i * BOT + quad * 4];
        acc.x += v.x; acc.y += v.y; acc.z += v.z; acc.w += v.w;
    }
    const float inv = 1.0f / (float)((e - s) > 0 ? (e - s) : 1);
    float m0 = acc.x * inv, m1 = acc.y * inv, m2 = acc.z * inv, m3 = acc.w * inv;
    unsigned short h0 = f2bf(m0), h1 = f2bf(m1), h2s = f2bf(m2), h3 = f2bf(m3);
    uint2 H, L;
    H.x = pack2(h0, h1); H.y = pack2(h2s, h3);
    L.x = pack2(f2bf(m0 - bf2f(h0)), f2bf(m1 - bf2f(h1)));
    L.y = pack2(f2bf(m2 - bf2f(h2s)), f2bf(m3 - bf2f(h3)));
    *(uint2*)&mH[(size_t)q * BOT + quad * 4] = H;
    *(uint2*)&mL[(size_t)q * BOT + quad * 4] = L;
}

// ---------------------------------------------------------------------------
// out[NQ,4] = g1[NQ,256] @ pw1[256,4] + pb1 : one wave per row
// ---------------------------------------------------------------------------
__global__ __launch_bounds__(256) void pred1_kernel(
    const float* __restrict__ g1, const float* __restrict__ w,
    const float* __restrict__ b, float* __restrict__ out)
{
    const int wave = threadIdx.x >> 6;
    const int lane = threadIdx.x & 63;
    const int row  = blockIdx.x * 4 + wave;

    const float* g = g1 + (size_t)row * 256;
    float a0 = 0, a1 = 0, a2 = 0, a3 = 0;
    #pragma unroll
    for (int i = 0; i < 4; ++i) {
        int k = lane + 64 * i;
        float gv = g[k];
        const float* wr = w + k * 4;
        a0 = fmaf(gv, wr[0], a0);
        a1 = fmaf(gv, wr[1], a1);
        a2 = fmaf(gv, wr[2], a2);
        a3 = fmaf(gv, wr[3], a3);
    }
    #pragma unroll
    for (int off = 32; off > 0; off >>= 1) {
        a0 += __shfl_down(a0, off, 64);
        a1 += __shfl_down(a1, off, 64);
        a2 += __shfl_down(a2, off, 64);
        a3 += __shfl_down(a3, off, 64);
    }
    if (lane == 0) {
        float4 o = {a0 + b[0], a1 + b[1], a2 + b[2], a3 + b[3]};
        *(float4*)&out[(size_t)row * 4] = o;
    }
}

// ---------------------------------------------------------------------------
extern "C" void kernel_launch(void* const* d_in, const int* in_sizes, int n_in,
                              void* d_out, int out_size, void* d_ws, size_t ws_size,
                              hipStream_t stream)
{
    const float* x    = (const float*)d_in[0];
    const float* qpos = (const float*)d_in[1];
    const int*   edges= (const int*)  d_in[2];
    const float* w0   = (const float*)d_in[3];
    const float* b0   = (const float*)d_in[4];
    const float* w1   = (const float*)d_in[5];
    const float* b1   = (const float*)d_in[6];
    const float* w2   = (const float*)d_in[7];
    const float* b2   = (const float*)d_in[8];
    const float* pw0  = (const float*)d_in[9];
    const float* pb0  = (const float*)d_in[10];
    const float* pw1  = (const float*)d_in[11];
    const float* pb1  = (const float*)d_in[12];
    float* out = (float*)d_out;

    char* ws = (char*)d_ws;
    float*          Zwin  = (float*)(ws + OFF_ZWIN);
    unsigned short* fxH   = (unsigned short*)(ws + OFF_FXH);
    unsigned short* fxL   = (unsigned short*)(ws + OFF_FXL);
    unsigned short* peH   = (unsigned short*)(ws + OFF_PEH);
    unsigned short* peL   = (unsigned short*)(ws + OFF_PEL);
    unsigned short* h0H   = (unsigned short*)(ws + OFF_H0H);
    unsigned short* h0L   = (unsigned short*)(ws + OFF_H0L);
    unsigned short* h1H   = (unsigned short*)(ws + OFF_H1H);
    unsigned short* h1L   = (unsigned short*)(ws + OFF_H1L);
    float*          h2    = (float*)(ws + OFF_H2);
    unsigned short* w0aH  = (unsigned short*)(ws + OFF_W0AH);
    unsigned short* w0aL  = (unsigned short*)(ws + OFF_W0AL);
    unsigned short* w0bH  = (unsigned short*)(ws + OFF_W0BH);
    unsigned short* w0bL  = (unsigned short*)(ws + OFF_W0BL);
    unsigned short* w1H   = (unsigned short*)(ws + OFF_W1H);
    unsigned short* w1L   = (unsigned short*)(ws + OFF_W1L);
    unsigned short* w2H   = (unsigned short*)(ws + OFF_W2H);
    unsigned short* w2L   = (unsigned short*)(ws + OFF_W2L);
    unsigned short* pw0H  = (unsigned short*)(ws + OFF_PW0H);
    unsigned short* pw0L  = (unsigned short*)(ws + OFF_PW0L);
    int*            start = (int*)(ws + OFF_START);
    int*            winlo = (int*)(ws + OFF_WINLO);
    unsigned short* meanH = (unsigned short*)(ws + OFF_MEANH);
    unsigned short* meanL = (unsigned short*)(ws + OFF_MEANL);
    float*          g1    = (float*)(ws + OFF_G1);

    // weight conversion: W0a = w0[0:256], W0b = w0[256:768]
    conv_w<<<(IN_DIM*H0_DIM + 255)/256, 256, 0, stream>>>(w0, w0aH, w0aL, IN_DIM, H0_DIM);
    conv_w<<<(H0_DIM*H0_DIM + 255)/256, 256, 0, stream>>>(w0 + (size_t)IN_DIM*H0_DIM, w0bH, w0bL, H0_DIM, H0_DIM);
    conv_w<<<(H0_DIM*H1_DIM + 255)/256, 256, 0, stream>>>(w1, w1H, w1L, H0_DIM, H1_DIM);
    conv_w<<<(H1_DIM*BOT + 255)/256, 256, 0, stream>>>(w2, w2H, w2L, H1_DIM, BOT);
    conv_w<<<(BOT*H1_DIM + 255)/256, 256, 0, stream>>>(pw0, pw0H, pw0L, BOT, H1_DIM);
    seg_offsets<<<(NE_ + 1 + 255)/256, 256, 0, stream>>>(edges, start);
    calc_winlo<<<1, 64, 0, stream>>>(edges, winlo);

    for (int c = 0; c < NCHUNK; ++c) {
        const int ebase = c * CH;
        // Z window: Z = PE @ W0b + b0 (fp32, no act)
        build_pe<<<ZWIN/4, 256, 0, stream>>>(qpos, winlo, c, peH, peL);
        gemm_mfma<0, 0><<<dim3(H0_DIM/128, ZWIN/128), 256, 0, stream>>>(
            peH, peL, w0bH, w0bL, b0, Zwin, nullptr, nullptr,
            ZWIN, H0_DIM, H0_DIM, nullptr, nullptr, nullptr);
        // edge layer-0: h0 = gelu(x[g] @ W0a + Z[q])
        build_featx<<<CH/4, 256, 0, stream>>>(x, edges, fxH, fxL, ebase);
        gemm_mfma<1, 2><<<dim3(H0_DIM/128, CH/128), 256, 0, stream>>>(
            fxH, fxL, w0aH, w0aL, nullptr, nullptr, h0H, h0L,
            CH, IN_DIM, H0_DIM, edges + 2*(size_t)ebase, Zwin, winlo + c);
        gemm_mfma<1, 1><<<dim3(H1_DIM/128, CH/128), 256, 0, stream>>>(
            h0H, h0L, w1H, w1L, b1, nullptr, h1H, h1L,
            CH, H0_DIM, H1_DIM, nullptr, nullptr, nullptr);
        gemm_mfma<0, 0><<<dim3(BOT/128, CH/128), 256, 0, stream>>>(
            h1H, h1L, w2H, w2L, b2, h2 + (size_t)ebase * BOT, nullptr, nullptr,
            CH, H1_DIM, BOT, nullptr, nullptr, nullptr);
    }

    seg_mean<<<NQ_/8, 256, 0, stream>>>(start, h2, meanH, meanL);
    gemm_mfma<1, 0><<<dim3(H1_DIM/128, NQ_/128), 256, 0, stream>>>(
        meanH, meanL, pw0H, pw0L, pb0, g1, nullptr, nullptr,
        NQ_, BOT, H1_DIM, nullptr, nullptr, nullptr);
    pred1_kernel<<<NQ_/4, 256, 0, stream>>>(g1, pw1, pb1, out);
}

// Round 5
// 2021.933 us; speedup vs baseline: 2.2875x; 1.1260x over previous
//
#include <hip/hip_runtime.h>
#include <cmath>

// Problem constants
#define IN_DIM   256
#define H0_DIM   512
#define H1_DIM   256
#define BOT      128
#define NQ_      131072
#define NE_      262144
#define SEQ_     262144
#define CH       65536
#define NCHUNK   (NE_/CH)
#define QWIN     32768
#define NWIN     (NQ_/QWIN)
#define PE_K     384          // PE cols 384..511 are constant -> folded into bias

// Workspace layout (bytes), ws = 1 GiB. Peak ~875 MB.
static const size_t OFF_XH    = 0;            // 262144*256*2 = 134217728
static const size_t OFF_XL    = 134217728;
static const size_t OFF_Z     = 268435456;    // 131072*512*4 = 268435456
static const size_t OFF_PEH   = 536870912;    // 32768*384*2 = 25165824 (phase: Z build)
static const size_t OFF_PEL   = 562036736;
static const size_t OFF_H0H   = 536870912;    // alias PE region (dead after Z) 67108864
static const size_t OFF_H0L   = 603979776;
static const size_t OFF_H1H   = 671088640;    // 33554432
static const size_t OFF_H1L   = 704643072;
static const size_t OFF_H2    = 738197504;    // 262144*128*4 = 134217728
static const size_t OFF_W0AH  = 872415232;    // [512][256] 262144
static const size_t OFF_W0AL  = 872677376;
static const size_t OFF_W0BH  = 872939520;    // [512][384] 393216
static const size_t OFF_W0BL  = 873332736;
static const size_t OFF_W1H   = 873725952;    // [256][512] 262144
static const size_t OFF_W1L   = 873988096;
static const size_t OFF_W2H   = 874250240;    // [128][256] 65536
static const size_t OFF_W2L   = 874315776;
static const size_t OFF_PW0H  = 874381312;    // [256][128] 65536
static const size_t OFF_PW0L  = 874446848;
static const size_t OFF_BCONST= 874512384;    // 512*4
static const size_t OFF_START = 874514432;    // (NQ+1)*4
// post-loop aliases
static const size_t OFF_MEANH = 0;            // alias xH (dead after chunk loop)
static const size_t OFF_MEANL = 33554432;
static const size_t OFF_G1    = 268435456;    // alias Z (dead after chunk loop)

typedef __attribute__((ext_vector_type(8))) short bf16x8;
typedef __attribute__((ext_vector_type(4))) float f32x4;

__device__ __forceinline__ float gelu_f(float v) {
    return v * 0.5f * (1.0f + erff(v * 0.7071067811865476f));
}
__device__ __forceinline__ unsigned short f2bf(float f) {
    unsigned int u = __float_as_uint(f);
    unsigned int r = (u + 0x7FFFu + ((u >> 16) & 1u)) >> 16;
    return (unsigned short)r;
}
__device__ __forceinline__ float bf2f(unsigned short h) {
    return __uint_as_float(((unsigned int)h) << 16);
}
__device__ __forceinline__ unsigned int pack2(unsigned short a, unsigned short b) {
    return (unsigned int)a | ((unsigned int)b << 16);
}
__device__ __forceinline__ void stage16(const void* g, void* l) {
    __builtin_amdgcn_global_load_lds(
        (const __attribute__((address_space(1))) unsigned int*)g,
        (__attribute__((address_space(3))) unsigned int*)l,
        16, 0, 0);
}

// ---------------------------------------------------------------------------
// x fp32 [SEQ][256] -> xH/xL bf16 (wave per row)
// ---------------------------------------------------------------------------
__global__ __launch_bounds__(256) void conv_x(
    const float* __restrict__ x,
    unsigned short* __restrict__ xH, unsigned short* __restrict__ xL)
{
    const int wv = threadIdx.x >> 6;
    const int l  = threadIdx.x & 63;
    const int row = blockIdx.x * 4 + wv;
    const size_t base = (size_t)row * IN_DIM + l * 4;
    float4 v = *(const float4*)&x[base];
    unsigned short h0 = f2bf(v.x), h1 = f2bf(v.y), h2 = f2bf(v.z), h3 = f2bf(v.w);
    uint2 H, L;
    H.x = pack2(h0, h1); H.y = pack2(h2, h3);
    L.x = pack2(f2bf(v.x - bf2f(h0)), f2bf(v.y - bf2f(h1)));
    L.y = pack2(f2bf(v.z - bf2f(h2)), f2bf(v.w - bf2f(h3)));
    *(uint2*)&xH[base] = H;
    *(uint2*)&xL[base] = L;
}

// ---------------------------------------------------------------------------
// Weight convert: W[K][N] fp32 -> WT hi/lo bf16 [N][K]
// ---------------------------------------------------------------------------
__global__ __launch_bounds__(256) void conv_w(
    const float* __restrict__ W, unsigned short* __restrict__ WTh,
    unsigned short* __restrict__ WTl, int K, int N)
{
    int idx = blockIdx.x * 256 + threadIdx.x;
    if (idx >= K * N) return;
    int k = idx / N, n = idx % N;
    float v = W[idx];
    unsigned short h = f2bf(v);
    WTh[(size_t)n * K + k] = h;
    WTl[(size_t)n * K + k] = f2bf(v - bf2f(h));
}

// ---------------------------------------------------------------------------
// bconst[n] = b0[n] + sum_j sin(om_j)*w0[640+j][n] + cos(om_j)*w0[704+j][n]
// (the cv=1.0 constant quarter of the PE, folded out of the Z GEMM)
// ---------------------------------------------------------------------------
__global__ __launch_bounds__(256) void bias_fold(
    const float* __restrict__ w0, const float* __restrict__ b0,
    float* __restrict__ bconst)
{
    int n = blockIdx.x * 256 + threadIdx.x;
    if (n >= H0_DIM) return;
    float s = b0[n];
    for (int j = 0; j < 64; ++j) {
        float om = exp2f((float)j * (-13.287712379549449f / 64.0f));
        s += sinf(om) * w0[(size_t)(640 + j) * H0_DIM + n];
        s += cosf(om) * w0[(size_t)(704 + j) * H0_DIM + n];
    }
    bconst[n] = s;
}

// ---------------------------------------------------------------------------
// start[q] = first edge index with qidx >= q (qidx sorted ascending)
// ---------------------------------------------------------------------------
__global__ __launch_bounds__(256) void seg_offsets(
    const int* __restrict__ edges, int* __restrict__ start)
{
    int e = blockIdx.x * 256 + threadIdx.x;
    if (e > NE_) return;
    int qc = (e < NE_) ? edges[2 * e] : NQ_;
    int qp = (e > 0) ? edges[2 * e - 2] : -1;
    for (int q = qp + 1; q <= qc; ++q) start[q] = e;
}

// ---------------------------------------------------------------------------
// PE build for window: rows i in [0,QWIN), query q = qbase+i, cols 0..383.
// Wave per row; lanes with i0>=384 idle.
// ---------------------------------------------------------------------------
__global__ __launch_bounds__(256) void build_pe(
    const float* __restrict__ qpos, int qbase,
    unsigned short* __restrict__ peH, unsigned short* __restrict__ peL)
{
    const int wv = threadIdx.x >> 6;
    const int l  = threadIdx.x & 63;
    const int i  = blockIdx.x * 4 + wv;
    const int i0 = l * 8;
    if (i0 >= PE_K) return;
    const int q  = qbase + i;
    const size_t base = (size_t)i * PE_K;

    const int cc = i0 >> 7;          // coord 0..2
    const int j0 = i0 & 127;
    const float cv = qpos[q * 3 + cc] * 0.01f - 1.0f;
    const bool is_sin = (j0 < 64);
    const int jj0 = j0 & 63;
    unsigned int hw[4], lw[4];
    #pragma unroll
    for (int p2 = 0; p2 < 4; ++p2) {
        unsigned short hh[2], ll[2];
        #pragma unroll
        for (int s = 0; s < 2; ++s) {
            int jj = jj0 + p2 * 2 + s;
            float om  = exp2f((float)jj * (-13.287712379549449f / 64.0f));
            float arg = cv * om;
            float v   = is_sin ? __sinf(arg) : __cosf(arg);
            unsigned short h = f2bf(v);
            hh[s] = h; ll[s] = f2bf(v - bf2f(h));
        }
        hw[p2] = pack2(hh[0], hh[1]);
        lw[p2] = pack2(ll[0], ll[1]);
    }
    uint4 H, L;
    H.x = hw[0]; H.y = hw[1]; H.z = hw[2]; H.w = hw[3];
    L.x = lw[0]; L.y = lw[1]; L.z = lw[2]; L.w = lw[3];
    *(uint4*)&peH[base + i0] = H;
    *(uint4*)&peL[base + i0] = L;
}

// ---------------------------------------------------------------------------
// Split-bf16 MFMA GEMM (3 passes AhBh+AhBl+AlBh). 128x128 tile, BK=32.
// GATHER: A row r -> xHL row gp[2*(bm+r)+1] (fused x gather).
// OUT_MODE 0: fp32 = [gelu](acc + bias)
// OUT_MODE 1: bf16 hi/lo via XOR-swizzled LDS transpose (bias+ACT)
// OUT_MODE 2: bf16 hi/lo, val = gelu(acc + Z[q]), q = gp[2*row] (no bias)
// ---------------------------------------------------------------------------
template <int ACT, int OUT_MODE, int GATHER>
__global__ __launch_bounds__(256) void gemm_mfma(
    const unsigned short* __restrict__ Ah, const unsigned short* __restrict__ Al,
    const unsigned short* __restrict__ Bh, const unsigned short* __restrict__ Bl,
    const float* __restrict__ bias,
    float* __restrict__ Cf, unsigned short* __restrict__ ChO, unsigned short* __restrict__ ClO,
    int M, int K, int N,
    const int* __restrict__ gp, const float* __restrict__ Zw)
{
    __shared__ __align__(16) short lds[4][128][32];   // 32 KB

    const int tid = threadIdx.x;
    const int w   = tid >> 6;
    const int l   = tid & 63;
    const int l16 = l & 15;
    const int lq  = l >> 4;
    const int bm  = blockIdx.y * 128;
    const int bn  = blockIdx.x * 128;
    const int wm  = (w & 1) * 64;
    const int wn  = (w >> 1) * 64;

    f32x4 acc[4][4];
    #pragma unroll
    for (int i = 0; i < 4; ++i)
        #pragma unroll
        for (int j = 0; j < 4; ++j)
            acc[i][j] = (f32x4){0.f, 0.f, 0.f, 0.f};

    const int jrow = l >> 2;
    const int jkc  = l & 3;
    const int t0 = w * 2, t1 = t0 + 1;
    const int r0 = t0 * 16 + jrow, r1 = t1 * 16 + jrow;

    size_t arow0, arow1;
    if (GATHER) {
        arow0 = (size_t)gp[2 * (bm + r0) + 1] * K;
        arow1 = (size_t)gp[2 * (bm + r1) + 1] * K;
    } else {
        arow0 = (size_t)(bm + r0) * K;
        arow1 = (size_t)(bm + r1) * K;
    }
    const size_t brow0 = (size_t)(bn + r0) * K;
    const size_t brow1 = (size_t)(bn + r1) * K;
    short* d00 = &lds[0][0][0] + t0 * 512;
    short* d01 = &lds[1][0][0] + t0 * 512;
    short* d02 = &lds[2][0][0] + t0 * 512;
    short* d03 = &lds[3][0][0] + t0 * 512;
    short* d10 = &lds[0][0][0] + t1 * 512;
    short* d11 = &lds[1][0][0] + t1 * 512;
    short* d12 = &lds[2][0][0] + t1 * 512;
    short* d13 = &lds[3][0][0] + t1 * 512;

    for (int k0 = 0; k0 < K; k0 += 32) {
        const int ko = k0 + jkc * 8;
        stage16(Ah + arow0 + ko, d00);
        stage16(Al + arow0 + ko, d01);
        stage16(Bh + brow0 + ko, d02);
        stage16(Bl + brow0 + ko, d03);
        stage16(Ah + arow1 + ko, d10);
        stage16(Al + arow1 + ko, d11);
        stage16(Bh + brow1 + ko, d12);
        stage16(Bl + brow1 + ko, d13);
        __syncthreads();

        bf16x8 ah[4], al[4], bh[4], bl[4];
        #pragma unroll
        for (int i = 0; i < 4; ++i) {
            ah[i] = *(const bf16x8*)&lds[0][wm + i*16 + l16][lq*8];
            al[i] = *(const bf16x8*)&lds[1][wm + i*16 + l16][lq*8];
            bh[i] = *(const bf16x8*)&lds[2][wn + i*16 + l16][lq*8];
            bl[i] = *(const bf16x8*)&lds[3][wn + i*16 + l16][lq*8];
        }
        #pragma unroll
        for (int i = 0; i < 4; ++i)
            #pragma unroll
            for (int j = 0; j < 4; ++j) {
                acc[i][j] = __builtin_amdgcn_mfma_f32_16x16x32_bf16(ah[i], bh[j], acc[i][j], 0, 0, 0);
                acc[i][j] = __builtin_amdgcn_mfma_f32_16x16x32_bf16(ah[i], bl[j], acc[i][j], 0, 0, 0);
                acc[i][j] = __builtin_amdgcn_mfma_f32_16x16x32_bf16(al[i], bh[j], acc[i][j], 0, 0, 0);
            }
        __syncthreads();
    }

    if (OUT_MODE == 0) {
        #pragma unroll
        for (int j = 0; j < 4; ++j) {
            int n = bn + wn + j * 16 + l16;
            float bv = bias[n];
            #pragma unroll
            for (int i = 0; i < 4; ++i) {
                int mrow = bm + wm + i * 16 + lq * 4;
                #pragma unroll
                for (int r = 0; r < 4; ++r) {
                    float v = acc[i][j][r] + bv;
                    if (ACT) v = gelu_f(v);
                    Cf[(size_t)(mrow + r) * N + n] = v;
                }
            }
        }
    } else if (OUT_MODE == 1) {
        float* lbuf = ((float*)&lds[0][0][0]) + w * 2048;
        #pragma unroll
        for (int h = 0; h < 2; ++h) {
            #pragma unroll
            for (int j2 = 0; j2 < 2; ++j2) {
                int j = 2 * h + j2;
                float bv = bias[bn + wn + j * 16 + l16];
                #pragma unroll
                for (int i = 0; i < 4; ++i) {
                    #pragma unroll
                    for (int r = 0; r < 4; ++r) {
                        int rowq = i * 16 + lq * 4 + r;
                        int col  = j2 * 16 + l16;
                        float v = acc[i][j][r] + bv;
                        if (ACT) v = gelu_f(v);
                        lbuf[rowq * 32 + (((col >> 2) ^ (rowq & 7)) << 2) + (col & 3)] = v;
                    }
                }
            }
            __syncthreads();
            {
                const size_t grow = (size_t)(bm + wm + l);
                unsigned short* ph = ChO + grow * N + bn + wn + h * 32;
                unsigned short* pl = ClO + grow * N + bn + wn + h * 32;
                #pragma unroll
                for (int cc = 0; cc < 4; ++cc) {
                    unsigned int hw[4], lw[4];
                    #pragma unroll
                    for (int c2 = 0; c2 < 2; ++c2) {
                        int cq = cc * 2 + c2;
                        float4 v = *(const float4*)&lbuf[l * 32 + ((cq ^ (l & 7)) << 2)];
                        unsigned short ha = f2bf(v.x), hb = f2bf(v.y);
                        unsigned short hc = f2bf(v.z), hd = f2bf(v.w);
                        hw[c2*2+0] = pack2(ha, hb);
                        hw[c2*2+1] = pack2(hc, hd);
                        lw[c2*2+0] = pack2(f2bf(v.x - bf2f(ha)), f2bf(v.y - bf2f(hb)));
                        lw[c2*2+1] = pack2(f2bf(v.z - bf2f(hc)), f2bf(v.w - bf2f(hd)));
                    }
                    uint4 H, L;
                    H.x = hw[0]; H.y = hw[1]; H.z = hw[2]; H.w = hw[3];
                    L.x = lw[0]; L.y = lw[1]; L.z = lw[2]; L.w = lw[3];
                    *(uint4*)&ph[cc * 8] = H;
                    *(uint4*)&pl[cc * 8] = L;
                }
            }
            __syncthreads();
        }
    } else {
        // OUT_MODE 2: raw transpose, then val = gelu(acc + Z[q][col])
        const int q = gp[2 * (bm + wm + l)];
        float* lbuf = ((float*)&lds[0][0][0]) + w * 2048;
        #pragma unroll
        for (int h = 0; h < 2; ++h) {
            #pragma unroll
            for (int j2 = 0; j2 < 2; ++j2) {
                int j = 2 * h + j2;
                #pragma unroll
                for (int i = 0; i < 4; ++i) {
                    #pragma unroll
                    for (int r = 0; r < 4; ++r) {
                        int rowq = i * 16 + lq * 4 + r;
                        int col  = j2 * 16 + l16;
                        lbuf[rowq * 32 + (((col >> 2) ^ (rowq & 7)) << 2) + (col & 3)] = acc[i][j][r];
                    }
                }
            }
            __syncthreads();
            {
                const size_t grow = (size_t)(bm + wm + l);
                const float* zrow = Zw + (size_t)q * H0_DIM + bn + wn + h * 32;
                unsigned short* ph = ChO + grow * N + bn + wn + h * 32;
                unsigned short* pl = ClO + grow * N + bn + wn + h * 32;
                #pragma unroll
                for (int cc = 0; cc < 4; ++cc) {
                    unsigned int hw[4], lw[4];
                    #pragma unroll
                    for (int c2 = 0; c2 < 2; ++c2) {
                        int cq = cc * 2 + c2;
                        float4 v = *(const float4*)&lbuf[l * 32 + ((cq ^ (l & 7)) << 2)];
                        float4 z = *(const float4*)&zrow[cq * 4];
                        v.x = gelu_f(v.x + z.x); v.y = gelu_f(v.y + z.y);
                        v.z = gelu_f(v.z + z.z); v.w = gelu_f(v.w + z.w);
                        unsigned short ha = f2bf(v.x), hb = f2bf(v.y);
                        unsigned short hc = f2bf(v.z), hd = f2bf(v.w);
                        hw[c2*2+0] = pack2(ha, hb);
                        hw[c2*2+1] = pack2(hc, hd);
                        lw[c2*2+0] = pack2(f2bf(v.x - bf2f(ha)), f2bf(v.y - bf2f(hb)));
                        lw[c2*2+1] = pack2(f2bf(v.z - bf2f(hc)), f2bf(v.w - bf2f(hd)));
                    }
                    uint4 H, L;
                    H.x = hw[0]; H.y = hw[1]; H.z = hw[2]; H.w = hw[3];
                    L.x = lw[0]; L.y = lw[1]; L.z = lw[2]; L.w = lw[3];
                    *(uint4*)&ph[cc * 8] = H;
                    *(uint4*)&pl[cc * 8] = L;
                }
            }
            __syncthreads();
        }
    }
}

// ---------------------------------------------------------------------------
// segment mean via precomputed offsets
// ---------------------------------------------------------------------------
__global__ __launch_bounds__(256) void seg_mean(
    const int* __restrict__ start, const float* __restrict__ h2,
    unsigned short* __restrict__ mH, unsigned short* __restrict__ mL)
{
    const int t = threadIdx.x;
    const int q = blockIdx.x * 8 + (t >> 5);
    const int quad = t & 31;
    const int s = start[q];
    const int e = start[q + 1];

    float4 acc = make_float4(0.f, 0.f, 0.f, 0.f);
    for (int i = s; i < e; ++i) {
        const float4 v = *(const float4*)&h2[(size_t)i * BOT + quad * 4];
        acc.x += v.x; acc.y += v.y; acc.z += v.z; acc.w += v.w;
    }
    const float inv = 1.0f / (float)((e - s) > 0 ? (e - s) : 1);
    float m0 = acc.x * inv, m1 = acc.y * inv, m2 = acc.z * inv, m3 = acc.w * inv;
    unsigned short h0 = f2bf(m0), h1 = f2bf(m1), h2s = f2bf(m2), h3 = f2bf(m3);
    uint2 H, L;
    H.x = pack2(h0, h1); H.y = pack2(h2s, h3);
    L.x = pack2(f2bf(m0 - bf2f(h0)), f2bf(m1 - bf2f(h1)));
    L.y = pack2(f2bf(m2 - bf2f(h2s)), f2bf(m3 - bf2f(h3)));
    *(uint2*)&mH[(size_t)q * BOT + quad * 4] = H;
    *(uint2*)&mL[(size_t)q * BOT + quad * 4] = L;
}

// ---------------------------------------------------------------------------
// out[NQ,4] = g1[NQ,256] @ pw1[256,4] + pb1 : one wave per row
// ---------------------------------------------------------------------------
__global__ __launch_bounds__(256) void pred1_kernel(
    const float* __restrict__ g1, const float* __restrict__ w,
    const float* __restrict__ b, float* __restrict__ out)
{
    const int wave = threadIdx.x >> 6;
    const int lane = threadIdx.x & 63;
    const int row  = blockIdx.x * 4 + wave;

    const float* g = g1 + (size_t)row * 256;
    float a0 = 0, a1 = 0, a2 = 0, a3 = 0;
    #pragma unroll
    for (int i = 0; i < 4; ++i) {
        int k = lane + 64 * i;
        float gv = g[k];
        const float* wr = w + k * 4;
        a0 = fmaf(gv, wr[0], a0);
        a1 = fmaf(gv, wr[1], a1);
        a2 = fmaf(gv, wr[2], a2);
        a3 = fmaf(gv, wr[3], a3);
    }
    #pragma unroll
    for (int off = 32; off > 0; off >>= 1) {
        a0 += __shfl_down(a0, off, 64);
        a1 += __shfl_down(a1, off, 64);
        a2 += __shfl_down(a2, off, 64);
        a3 += __shfl_down(a3, off, 64);
    }
    if (lane == 0) {
        float4 o = {a0 + b[0], a1 + b[1], a2 + b[2], a3 + b[3]};
        *(float4*)&out[(size_t)row * 4] = o;
    }
}

// ---------------------------------------------------------------------------
extern "C" void kernel_launch(void* const* d_in, const int* in_sizes, int n_in,
                              void* d_out, int out_size, void* d_ws, size_t ws_size,
                              hipStream_t stream)
{
    const float* x    = (const float*)d_in[0];
    const float* qpos = (const float*)d_in[1];
    const int*   edges= (const int*)  d_in[2];
    const float* w0   = (const float*)d_in[3];
    const float* b0   = (const float*)d_in[4];
    const float* w1   = (const float*)d_in[5];
    const float* b1   = (const float*)d_in[6];
    const float* w2   = (const float*)d_in[7];
    const float* b2   = (const float*)d_in[8];
    const float* pw0  = (const float*)d_in[9];
    const float* pb0  = (const float*)d_in[10];
    const float* pw1  = (const float*)d_in[11];
    const float* pb1  = (const float*)d_in[12];
    float* out = (float*)d_out;

    char* ws = (char*)d_ws;
    unsigned short* xH    = (unsigned short*)(ws + OFF_XH);
    unsigned short* xL    = (unsigned short*)(ws + OFF_XL);
    float*          Z     = (float*)(ws + OFF_Z);
    unsigned short* peH   = (unsigned short*)(ws + OFF_PEH);
    unsigned short* peL   = (unsigned short*)(ws + OFF_PEL);
    unsigned short* h0H   = (unsigned short*)(ws + OFF_H0H);
    unsigned short* h0L   = (unsigned short*)(ws + OFF_H0L);
    unsigned short* h1H   = (unsigned short*)(ws + OFF_H1H);
    unsigned short* h1L   = (unsigned short*)(ws + OFF_H1L);
    float*          h2    = (float*)(ws + OFF_H2);
    unsigned short* w0aH  = (unsigned short*)(ws + OFF_W0AH);
    unsigned short* w0aL  = (unsigned short*)(ws + OFF_W0AL);
    unsigned short* w0bH  = (unsigned short*)(ws + OFF_W0BH);
    unsigned short* w0bL  = (unsigned short*)(ws + OFF_W0BL);
    unsigned short* w1H   = (unsigned short*)(ws + OFF_W1H);
    unsigned short* w1L   = (unsigned short*)(ws + OFF_W1L);
    unsigned short* w2H   = (unsigned short*)(ws + OFF_W2H);
    unsigned short* w2L   = (unsigned short*)(ws + OFF_W2L);
    unsigned short* pw0H  = (unsigned short*)(ws + OFF_PW0H);
    unsigned short* pw0L  = (unsigned short*)(ws + OFF_PW0L);
    float*          bconst= (float*)(ws + OFF_BCONST);
    int*            start = (int*)(ws + OFF_START);
    unsigned short* meanH = (unsigned short*)(ws + OFF_MEANH);
    unsigned short* meanL = (unsigned short*)(ws + OFF_MEANL);
    float*          g1    = (float*)(ws + OFF_G1);

    // one-time conversions
    conv_x<<<SEQ_/4, 256, 0, stream>>>(x, xH, xL);
    conv_w<<<(IN_DIM*H0_DIM + 255)/256, 256, 0, stream>>>(w0, w0aH, w0aL, IN_DIM, H0_DIM);
    conv_w<<<(PE_K*H0_DIM + 255)/256, 256, 0, stream>>>(w0 + (size_t)IN_DIM*H0_DIM, w0bH, w0bL, PE_K, H0_DIM);
    conv_w<<<(H0_DIM*H1_DIM + 255)/256, 256, 0, stream>>>(w1, w1H, w1L, H0_DIM, H1_DIM);
    conv_w<<<(H1_DIM*BOT + 255)/256, 256, 0, stream>>>(w2, w2H, w2L, H1_DIM, BOT);
    conv_w<<<(BOT*H1_DIM + 255)/256, 256, 0, stream>>>(pw0, pw0H, pw0L, BOT, H1_DIM);
    bias_fold<<<2, 256, 0, stream>>>(w0, b0, bconst);
    seg_offsets<<<(NE_ + 1 + 255)/256, 256, 0, stream>>>(edges, start);

    // Z = PE @ W0b' + bconst for all queries (4 L3-resident PE windows)
    for (int wn = 0; wn < NWIN; ++wn) {
        build_pe<<<QWIN/4, 256, 0, stream>>>(qpos, wn * QWIN, peH, peL);
        gemm_mfma<0, 0, 0><<<dim3(H0_DIM/128, QWIN/128), 256, 0, stream>>>(
            peH, peL, w0bH, w0bL, bconst, Z + (size_t)wn * QWIN * H0_DIM,
            nullptr, nullptr, QWIN, PE_K, H0_DIM, nullptr, nullptr);
    }

    // edge pipeline, 4 chunks
    for (int c = 0; c < NCHUNK; ++c) {
        const int ebase = c * CH;
        gemm_mfma<1, 2, 1><<<dim3(H0_DIM/128, CH/128), 256, 0, stream>>>(
            xH, xL, w0aH, w0aL, nullptr, nullptr, h0H, h0L,
            CH, IN_DIM, H0_DIM, edges + 2*(size_t)ebase, Z);
        gemm_mfma<1, 1, 0><<<dim3(H1_DIM/128, CH/128), 256, 0, stream>>>(
            h0H, h0L, w1H, w1L, b1, nullptr, h1H, h1L,
            CH, H0_DIM, H1_DIM, nullptr, nullptr);
        gemm_mfma<0, 0, 0><<<dim3(BOT/128, CH/128), 256, 0, stream>>>(
            h1H, h1L, w2H, w2L, b2, h2 + (size_t)ebase * BOT, nullptr, nullptr,
            CH, H1_DIM, BOT, nullptr, nullptr);
    }

    seg_mean<<<NQ_/8, 256, 0, stream>>>(start, h2, meanH, meanL);
    gemm_mfma<1, 0, 0><<<dim3(H1_DIM/128, NQ_/128), 256, 0, stream>>>(
        meanH, meanL, pw0H, pw0L, pb0, g1, nullptr, nullptr,
        NQ_, BOT, H1_DIM, nullptr, nullptr);
    pred1_kernel<<<NQ_/4, 256, 0, stream>>>(g1, pw1, pb1, out);
}